// Round 1
// baseline (1418.511 us; speedup 1.0000x reference)
//
#include <hip/hip_runtime.h>

// ---------------- constants ----------------
#define HIDW 64
#define EPSV 1e-5f

// ---------------- CSR build ----------------
__global__ __launch_bounds__(256) void k_zero2(int* __restrict__ a, int* __restrict__ b, int n) {
    int i = blockIdx.x * 256 + threadIdx.x;
    if (i < n) { a[i] = 0; b[i] = 0; }
}

__global__ __launch_bounds__(256) void k_count(const int* __restrict__ dstv, int* __restrict__ deg, int e) {
    int i = blockIdx.x * 256 + threadIdx.x;
    if (i < e) atomicAdd(&deg[dstv[i]], 1);
}

__global__ __launch_bounds__(256) void k_dinv(const int* __restrict__ deg, float* __restrict__ dinv, int n) {
    int i = blockIdx.x * 256 + threadIdx.x;
    if (i < n) dinv[i] = rsqrtf(1.0f + (float)deg[i]);
}

// exclusive scan, 3-phase (chunk=256)
__global__ __launch_bounds__(256) void k_scan1(const int* __restrict__ deg, int* __restrict__ off,
                                               int* __restrict__ bsum, int n) {
    __shared__ int s[256];
    int tid = threadIdx.x;
    int i = blockIdx.x * 256 + tid;
    int v = (i < n) ? deg[i] : 0;
    s[tid] = v;
    __syncthreads();
    for (int o = 1; o < 256; o <<= 1) {
        int t = (tid >= o) ? s[tid - o] : 0;
        __syncthreads();
        s[tid] += t;
        __syncthreads();
    }
    if (i < n) off[i] = s[tid] - v;
    if (tid == 255) bsum[blockIdx.x] = s[255];
}

__global__ __launch_bounds__(512) void k_scan2(int* __restrict__ bsum, int nb) {
    __shared__ int s[512];
    int tid = threadIdx.x;
    int v = (tid < nb) ? bsum[tid] : 0;
    s[tid] = v;
    __syncthreads();
    for (int o = 1; o < 512; o <<= 1) {
        int t = (tid >= o) ? s[tid - o] : 0;
        __syncthreads();
        s[tid] += t;
        __syncthreads();
    }
    if (tid < nb) bsum[tid] = s[tid] - v;
}

__global__ __launch_bounds__(256) void k_scan3(int* __restrict__ off, const int* __restrict__ bsum, int n) {
    int i = blockIdx.x * 256 + threadIdx.x;
    if (i < n) off[i] += bsum[blockIdx.x];
}

__global__ __launch_bounds__(256) void k_fill(const int* __restrict__ srcv, const int* __restrict__ dstv,
                                              const int* __restrict__ off, int* __restrict__ cur,
                                              int* __restrict__ csr, int e) {
    int i = blockIdx.x * 256 + threadIdx.x;
    if (i < e) {
        int d = dstv[i];
        int p = off[d] + atomicAdd(&cur[d], 1);
        csr[p] = srcv[i];
    }
}

// ---------------- GEMM: hw[N,64] = h[N,K] @ W[K,64] ----------------
// block = 256 threads = 4 waves; wave handles 4 nodes x 64 outputs (lane=fo).
// W staged transposed in LDS (stride K+4, keeps float4 alignment + bank spread).
template <int K>
__global__ __launch_bounds__(256) void k_gemm(const float* __restrict__ h, const float* __restrict__ W,
                                              float* __restrict__ hw, int n) {
    __shared__ float sWt[64 * (K + 4)];
    int tid = threadIdx.x;
    for (int i = tid; i < K * 64; i += 256) {
        int k = i >> 6, fo = i & 63;
        sWt[fo * (K + 4) + k] = W[i];
    }
    __syncthreads();
    int lane = tid & 63, warp = tid >> 6;
    int nb = blockIdx.x * 16 + warp * 4;
    const float4* wrow = (const float4*)(sWt + lane * (K + 4));
    const float* hp[4];
#pragma unroll
    for (int j = 0; j < 4; ++j) {
        int nn = nb + j;
        if (nn >= n) nn = n - 1;
        hp[j] = h + (size_t)nn * K;
    }
    float acc[4] = {0.f, 0.f, 0.f, 0.f};
    for (int kc = 0; kc < K / 4; ++kc) {
        float4 w4 = wrow[kc];
#pragma unroll
        for (int j = 0; j < 4; ++j) {
            float4 h4 = ((const float4*)hp[j])[kc];
            acc[j] = fmaf(h4.x, w4.x, acc[j]);
            acc[j] = fmaf(h4.y, w4.y, acc[j]);
            acc[j] = fmaf(h4.z, w4.z, acc[j]);
            acc[j] = fmaf(h4.w, w4.w, acc[j]);
        }
    }
#pragma unroll
    for (int j = 0; j < 4; ++j) {
        if (nb + j < n) hw[(size_t)(nb + j) * HIDW + lane] = acc[j];
    }
}

// ---------------- gather-aggregate: one wave per node, lane = channel ----------------
__global__ __launch_bounds__(256) void k_gather(const float* __restrict__ hw, const int* __restrict__ csr,
                                                const int* __restrict__ off, const int* __restrict__ deg,
                                                const float* __restrict__ dinv, const float* __restrict__ bias,
                                                float* __restrict__ agg, int n) {
    int tid = threadIdx.x;
    int lane = tid & 63;
    int v = blockIdx.x * 4 + (tid >> 6);
    if (v >= n) return;
    float dv = dinv[v];
    // self loop + bias
    float acc = bias[lane] + hw[(size_t)v * HIDW + lane] * dv * dv;
    int s0 = off[v];
    int cnt = deg[v];
    int i = 0;
    for (; i + 2 <= cnt; i += 2) {
        int a = csr[s0 + i];
        int b = csr[s0 + i + 1];
        float wa = dinv[a] * dv;
        float wb = dinv[b] * dv;
        acc += hw[(size_t)a * HIDW + lane] * wa + hw[(size_t)b * HIDW + lane] * wb;
    }
    if (i < cnt) {
        int a = csr[s0 + i];
        acc += hw[(size_t)a * HIDW + lane] * (dinv[a] * dv);
    }
    agg[(size_t)v * HIDW + lane] = acc;
}

// ---------------- BatchNorm (training-mode batch stats) + ReLU ----------------
__global__ void k_stats_zero(float* __restrict__ st) {
    int i = threadIdx.x;
    if (i < 128) st[i] = 0.f;
}

__global__ __launch_bounds__(256) void k_stats_acc(const float* __restrict__ a, float* __restrict__ st, int n) {
    __shared__ float ss[256];
    __shared__ float sq[256];
    int tid = threadIdx.x;
    int c = tid & 63;
    int r = tid >> 6;
    float s = 0.f, q = 0.f;
    for (int nd = blockIdx.x * 4 + r; nd < n; nd += gridDim.x * 4) {
        float v = a[(size_t)nd * HIDW + c];
        s += v;
        q += v * v;
    }
    ss[tid] = s;
    sq[tid] = q;
    __syncthreads();
    if (tid < 64) {
        float S = ss[tid] + ss[tid + 64] + ss[tid + 128] + ss[tid + 192];
        float Q = sq[tid] + sq[tid + 64] + sq[tid + 128] + sq[tid + 192];
        atomicAdd(&st[c], S);
        atomicAdd(&st[64 + c], Q);
    }
}

__global__ void k_stats_fin(float* __restrict__ st, float invn) {
    int c = threadIdx.x;
    if (c < 64) {
        float mu = st[c] * invn;
        float var = st[64 + c] * invn - mu * mu;
        var = fmaxf(var, 0.f);
        st[c] = mu;
        st[64 + c] = rsqrtf(var + EPSV);
    }
}

__global__ __launch_bounds__(256) void k_bn_relu(float* __restrict__ a, const float* __restrict__ st,
                                                 const float* __restrict__ g, const float* __restrict__ bt,
                                                 int total) {
    int i = blockIdx.x * 256 + threadIdx.x;
    if (i < total) {
        int c = i & 63;
        float y = (a[i] - st[c]) * st[64 + c] * g[c] + bt[c];
        a[i] = fmaxf(y, 0.f);
    }
}

// ---------------- MLP head: out = relu(h@lw1+lb1)@lw2+lb2 ----------------
__global__ __launch_bounds__(256) void k_head(const float* __restrict__ h, const float* __restrict__ lw1,
                                              const float* __restrict__ lb1, const float* __restrict__ lw2,
                                              const float* __restrict__ lb2, float* __restrict__ out, int n) {
    __shared__ float sW[64 * 32];
    __shared__ float sb1[32];
    __shared__ float sw2[32];
    int tid = threadIdx.x;
    for (int i = tid; i < 64 * 32; i += 256) sW[i] = lw1[i];
    if (tid < 32) {
        sb1[tid] = lb1[tid];
        sw2[tid] = lw2[tid];
    }
    __syncthreads();
    int nd = blockIdx.x * 256 + tid;
    if (nd >= n) return;
    float acc[32];
#pragma unroll
    for (int j = 0; j < 32; ++j) acc[j] = sb1[j];
    const float4* hr = (const float4*)(h + (size_t)nd * HIDW);
#pragma unroll
    for (int kc = 0; kc < 16; ++kc) {
        float4 h4 = hr[kc];
        const float* w0 = &sW[(kc * 4 + 0) * 32];
        const float* w1 = &sW[(kc * 4 + 1) * 32];
        const float* w2 = &sW[(kc * 4 + 2) * 32];
        const float* w3 = &sW[(kc * 4 + 3) * 32];
#pragma unroll
        for (int j = 0; j < 32; ++j) {
            float t = fmaf(h4.x, w0[j], fmaf(h4.y, w1[j], fmaf(h4.z, w2[j], h4.w * w3[j])));
            acc[j] += t;
        }
    }
    float o = lb2[0];
#pragma unroll
    for (int j = 0; j < 32; ++j) o = fmaf(fmaxf(acc[j], 0.f), sw2[j], o);
    out[nd] = o;
}

// ---------------- launch ----------------
extern "C" void kernel_launch(void* const* d_in, const int* in_sizes, int n_in,
                              void* d_out, int out_size, void* d_ws, size_t ws_size,
                              hipStream_t stream) {
    const float* x = (const float*)d_in[0];
    const int* ei = (const int*)d_in[1];
    const float* W[3] = {(const float*)d_in[2], (const float*)d_in[6], (const float*)d_in[10]};
    const float* B[3] = {(const float*)d_in[3], (const float*)d_in[7], (const float*)d_in[11]};
    const float* G[3] = {(const float*)d_in[4], (const float*)d_in[8], (const float*)d_in[12]};
    const float* BT[3] = {(const float*)d_in[5], (const float*)d_in[9], (const float*)d_in[13]};
    const float* lw1 = (const float*)d_in[14];
    const float* lb1 = (const float*)d_in[15];
    const float* lw2 = (const float*)d_in[16];
    const float* lb2 = (const float*)d_in[17];
    float* out = (float*)d_out;

    const int n = in_sizes[0] / 128;  // 100000
    const int e = in_sizes[1] / 2;    // 1600000
    const int* srcv = ei;
    const int* dstv = ei + e;

    // workspace carve-up (all fully re-initialized every call)
    char* ws = (char*)d_ws;
    size_t off = 0;
    auto alloc = [&](size_t bytes) -> char* {
        off = (off + 511) & ~(size_t)511;
        char* p = ws + off;
        off += bytes;
        return p;
    };
    float* stats = (float*)alloc(512);
    float* dinv = (float*)alloc((size_t)n * 4);
    int* deg = (int*)alloc((size_t)n * 4);
    int* cur = (int*)alloc((size_t)n * 4);
    int* roff = (int*)alloc((size_t)(n + 1) * 4);
    int* bsum = (int*)alloc(512 * 4);
    int* csr = (int*)alloc((size_t)e * 4);
    float* bufA = (float*)alloc((size_t)n * HIDW * 4);
    float* bufB = (float*)alloc((size_t)n * HIDW * 4);

    const int gN = (n + 255) / 256;   // 391
    const int gE = (e + 255) / 256;   // 6250
    const int gG = (n + 15) / 16;     // 6250 (gemm: 16 nodes/block)
    const int gV = (n + 3) / 4;       // 25000 (gather: 4 nodes/block)

    // CSR build + degree norm
    k_zero2<<<gN, 256, 0, stream>>>(deg, cur, n);
    k_count<<<gE, 256, 0, stream>>>(dstv, deg, e);
    k_scan1<<<gN, 256, 0, stream>>>(deg, roff, bsum, n);
    k_scan2<<<1, 512, 0, stream>>>(bsum, gN);
    k_scan3<<<gN, 256, 0, stream>>>(roff, bsum, n);
    k_dinv<<<gN, 256, 0, stream>>>(deg, dinv, n);
    k_fill<<<gE, 256, 0, stream>>>(srcv, dstv, roff, cur, csr, e);

    // 3 GCN layers
    for (int L = 0; L < 3; ++L) {
        if (L == 0)
            k_gemm<128><<<gG, 256, 0, stream>>>(x, W[0], bufB, n);
        else
            k_gemm<64><<<gG, 256, 0, stream>>>(bufA, W[L], bufB, n);
        k_gather<<<gV, 256, 0, stream>>>(bufB, csr, roff, deg, dinv, B[L], bufA, n);
        k_stats_zero<<<1, 128, 0, stream>>>(stats);
        k_stats_acc<<<200, 256, 0, stream>>>(bufA, stats, n);
        k_stats_fin<<<1, 64, 0, stream>>>(stats, 1.0f / (float)n);
        k_bn_relu<<<(n * HIDW + 255) / 256, 256, 0, stream>>>(bufA, stats, G[L], BT[L], n * HIDW);
    }

    // head
    k_head<<<gN, 256, 0, stream>>>(bufA, lw1, lb1, lw2, lb2, out, n);
}

// Round 3
// 928.840 us; speedup vs baseline: 1.5272x; 1.5272x over previous
//
#include <hip/hip_runtime.h>

// ---------------- constants ----------------
#define HIDW 64
#define EPSV 1e-5f

// ---------------- CSR build ----------------
__global__ __launch_bounds__(256) void k_zero2(int* __restrict__ a, int* __restrict__ b, int n) {
    int i = blockIdx.x * 256 + threadIdx.x;
    if (i < n) { a[i] = 0; b[i] = 0; }
}

__global__ __launch_bounds__(256) void k_count(const int* __restrict__ dstv, int* __restrict__ deg, int e) {
    int i = blockIdx.x * 256 + threadIdx.x;
    if (i < e) atomicAdd(&deg[dstv[i]], 1);
}

__global__ __launch_bounds__(256) void k_dinv(const int* __restrict__ deg, float* __restrict__ dinv, int n) {
    int i = blockIdx.x * 256 + threadIdx.x;
    if (i < n) dinv[i] = rsqrtf(1.0f + (float)deg[i]);
}

// exclusive scan, 3-phase (chunk=256)
__global__ __launch_bounds__(256) void k_scan1(const int* __restrict__ deg, int* __restrict__ off,
                                               int* __restrict__ bsum, int n) {
    __shared__ int s[256];
    int tid = threadIdx.x;
    int i = blockIdx.x * 256 + tid;
    int v = (i < n) ? deg[i] : 0;
    s[tid] = v;
    __syncthreads();
    for (int o = 1; o < 256; o <<= 1) {
        int t = (tid >= o) ? s[tid - o] : 0;
        __syncthreads();
        s[tid] += t;
        __syncthreads();
    }
    if (i < n) off[i] = s[tid] - v;
    if (tid == 255) bsum[blockIdx.x] = s[255];
}

__global__ __launch_bounds__(512) void k_scan2(int* __restrict__ bsum, int nb) {
    __shared__ int s[512];
    int tid = threadIdx.x;
    int v = (tid < nb) ? bsum[tid] : 0;
    s[tid] = v;
    __syncthreads();
    for (int o = 1; o < 512; o <<= 1) {
        int t = (tid >= o) ? s[tid - o] : 0;
        __syncthreads();
        s[tid] += t;
        __syncthreads();
    }
    if (tid < nb) bsum[tid] = s[tid] - v;
}

__global__ __launch_bounds__(256) void k_scan3(int* __restrict__ off, const int* __restrict__ bsum, int n) {
    int i = blockIdx.x * 256 + threadIdx.x;
    if (i < n) off[i] += bsum[blockIdx.x];
}

__global__ __launch_bounds__(256) void k_fill(const int* __restrict__ srcv, const int* __restrict__ dstv,
                                              const int* __restrict__ off, int* __restrict__ cur,
                                              int* __restrict__ csr, int e) {
    int i = blockIdx.x * 256 + threadIdx.x;
    if (i < e) {
        int d = dstv[i];
        int p = off[d] + atomicAdd(&cur[d], 1);
        csr[p] = srcv[i];
    }
}

// ---------------- GEMM: hw[N,64] = h[N,K] @ W[K,64] ----------------
// block = 256 threads = 4 waves; wave handles 8 nodes, lane = output channel.
// W in NATURAL [k][fo] layout in LDS: lane reads sW[k*64+lane] -> bank = lane%32,
// 2-way aliasing = free (m136). h row loads are wave-uniform float4 broadcasts.
// #pragma unroll 2 caps live ranges (round-1 spill: VGPR=256, 775MB scratch writes).
template <int K>
__global__ __launch_bounds__(256) void k_gemm(const float* __restrict__ h, const float* __restrict__ W,
                                              float* __restrict__ hw, int n) {
    __shared__ float sW[K * 64];
    int tid = threadIdx.x;
    for (int i = tid; i < K * 64; i += 256) sW[i] = W[i];
    __syncthreads();
    int lane = tid & 63, warp = tid >> 6;
    int nb = blockIdx.x * 32 + warp * 8;
    if (nb >= n) return;
    const int KC = K / 4;  // K in float4 units
    const float4* h4p = (const float4*)h;
    size_t base[8];
#pragma unroll
    for (int j = 0; j < 8; ++j) {
        int nn = nb + j;
        if (nn >= n) nn = n - 1;
        base[j] = (size_t)nn * KC;
    }
    float acc[8] = {0.f, 0.f, 0.f, 0.f, 0.f, 0.f, 0.f, 0.f};
#pragma unroll 2
    for (int kc = 0; kc < KC; ++kc) {
        float w0 = sW[(kc * 4 + 0) * 64 + lane];
        float w1 = sW[(kc * 4 + 1) * 64 + lane];
        float w2 = sW[(kc * 4 + 2) * 64 + lane];
        float w3 = sW[(kc * 4 + 3) * 64 + lane];
#pragma unroll
        for (int j = 0; j < 8; ++j) {
            float4 h4 = h4p[base[j] + kc];
            acc[j] = fmaf(h4.x, w0, acc[j]);
            acc[j] = fmaf(h4.y, w1, acc[j]);
            acc[j] = fmaf(h4.z, w2, acc[j]);
            acc[j] = fmaf(h4.w, w3, acc[j]);
        }
    }
#pragma unroll
    for (int j = 0; j < 8; ++j) {
        if (nb + j < n) hw[(size_t)(nb + j) * HIDW + lane] = acc[j];
    }
}

// ---------------- gather-aggregate: one wave per node, lane = channel ----------------
__global__ __launch_bounds__(256) void k_gather(const float* __restrict__ hw, const int* __restrict__ csr,
                                                const int* __restrict__ off, const int* __restrict__ deg,
                                                const float* __restrict__ dinv, const float* __restrict__ bias,
                                                float* __restrict__ agg, int n) {
    int tid = threadIdx.x;
    int lane = tid & 63;
    int v = blockIdx.x * 4 + (tid >> 6);
    if (v >= n) return;
    float dv = dinv[v];
    // self loop + bias
    float acc = bias[lane] + hw[(size_t)v * HIDW + lane] * dv * dv;
    int s0 = off[v];
    int cnt = deg[v];
    int i = 0;
    for (; i + 2 <= cnt; i += 2) {
        int a = csr[s0 + i];
        int b = csr[s0 + i + 1];
        float wa = dinv[a] * dv;
        float wb = dinv[b] * dv;
        acc += hw[(size_t)a * HIDW + lane] * wa + hw[(size_t)b * HIDW + lane] * wb;
    }
    if (i < cnt) {
        int a = csr[s0 + i];
        acc += hw[(size_t)a * HIDW + lane] * (dinv[a] * dv);
    }
    agg[(size_t)v * HIDW + lane] = acc;
}

// ---------------- BatchNorm (training-mode batch stats) + ReLU ----------------
__global__ void k_stats_zero(float* __restrict__ st) {
    int i = threadIdx.x;
    if (i < 128) st[i] = 0.f;
}

__global__ __launch_bounds__(256) void k_stats_acc(const float* __restrict__ a, float* __restrict__ st, int n) {
    __shared__ float ss[256];
    __shared__ float sq[256];
    int tid = threadIdx.x;
    int c = tid & 63;
    int r = tid >> 6;
    float s = 0.f, q = 0.f;
    for (int nd = blockIdx.x * 4 + r; nd < n; nd += gridDim.x * 4) {
        float v = a[(size_t)nd * HIDW + c];
        s += v;
        q += v * v;
    }
    ss[tid] = s;
    sq[tid] = q;
    __syncthreads();
    if (tid < 64) {
        float S = ss[tid] + ss[tid + 64] + ss[tid + 128] + ss[tid + 192];
        float Q = sq[tid] + sq[tid + 64] + sq[tid + 128] + sq[tid + 192];
        atomicAdd(&st[c], S);
        atomicAdd(&st[64 + c], Q);
    }
}

__global__ void k_stats_fin(float* __restrict__ st, float invn) {
    int c = threadIdx.x;
    if (c < 64) {
        float mu = st[c] * invn;
        float var = st[64 + c] * invn - mu * mu;
        var = fmaxf(var, 0.f);
        st[c] = mu;
        st[64 + c] = rsqrtf(var + EPSV);
    }
}

__global__ __launch_bounds__(256) void k_bn_relu(float* __restrict__ a, const float* __restrict__ st,
                                                 const float* __restrict__ g, const float* __restrict__ bt,
                                                 int total) {
    int i = blockIdx.x * 256 + threadIdx.x;
    if (i < total) {
        int c = i & 63;
        float y = (a[i] - st[c]) * st[64 + c] * g[c] + bt[c];
        a[i] = fmaxf(y, 0.f);
    }
}

// ---------------- MLP head: out = relu(h@lw1+lb1)@lw2+lb2 ----------------
__global__ __launch_bounds__(256) void k_head(const float* __restrict__ h, const float* __restrict__ lw1,
                                              const float* __restrict__ lb1, const float* __restrict__ lw2,
                                              const float* __restrict__ lb2, float* __restrict__ out, int n) {
    __shared__ float sW[64 * 32];
    __shared__ float sb1[32];
    __shared__ float sw2[32];
    int tid = threadIdx.x;
    for (int i = tid; i < 64 * 32; i += 256) sW[i] = lw1[i];
    if (tid < 32) {
        sb1[tid] = lb1[tid];
        sw2[tid] = lw2[tid];
    }
    __syncthreads();
    int nd = blockIdx.x * 256 + tid;
    if (nd >= n) return;
    float acc[32];
#pragma unroll
    for (int j = 0; j < 32; ++j) acc[j] = sb1[j];
    const float4* hr = (const float4*)(h + (size_t)nd * HIDW);
#pragma unroll 4
    for (int kc = 0; kc < 16; ++kc) {
        float4 h4 = hr[kc];
        const float* w0 = &sW[(kc * 4 + 0) * 32];
        const float* w1 = &sW[(kc * 4 + 1) * 32];
        const float* w2 = &sW[(kc * 4 + 2) * 32];
        const float* w3 = &sW[(kc * 4 + 3) * 32];
#pragma unroll
        for (int j = 0; j < 32; ++j) {
            float t = fmaf(h4.x, w0[j], fmaf(h4.y, w1[j], fmaf(h4.z, w2[j], h4.w * w3[j])));
            acc[j] += t;
        }
    }
    float o = lb2[0];
#pragma unroll
    for (int j = 0; j < 32; ++j) o = fmaf(fmaxf(acc[j], 0.f), sw2[j], o);
    out[nd] = o;
}

// ---------------- launch ----------------
extern "C" void kernel_launch(void* const* d_in, const int* in_sizes, int n_in,
                              void* d_out, int out_size, void* d_ws, size_t ws_size,
                              hipStream_t stream) {
    const float* x = (const float*)d_in[0];
    const int* ei = (const int*)d_in[1];
    const float* W[3] = {(const float*)d_in[2], (const float*)d_in[6], (const float*)d_in[10]};
    const float* B[3] = {(const float*)d_in[3], (const float*)d_in[7], (const float*)d_in[11]};
    const float* G[3] = {(const float*)d_in[4], (const float*)d_in[8], (const float*)d_in[12]};
    const float* BT[3] = {(const float*)d_in[5], (const float*)d_in[9], (const float*)d_in[13]};
    const float* lw1 = (const float*)d_in[14];
    const float* lb1 = (const float*)d_in[15];
    const float* lw2 = (const float*)d_in[16];
    const float* lb2 = (const float*)d_in[17];
    float* out = (float*)d_out;

    const int n = in_sizes[0] / 128;  // 100000
    const int e = in_sizes[1] / 2;    // 1600000
    const int* srcv = ei;
    const int* dstv = ei + e;

    // workspace carve-up (all fully re-initialized every call)
    char* ws = (char*)d_ws;
    size_t off = 0;
    auto alloc = [&](size_t bytes) -> char* {
        off = (off + 511) & ~(size_t)511;
        char* p = ws + off;
        off += bytes;
        return p;
    };
    float* stats = (float*)alloc(512);
    float* dinv = (float*)alloc((size_t)n * 4);
    int* deg = (int*)alloc((size_t)n * 4);
    int* cur = (int*)alloc((size_t)n * 4);
    int* roff = (int*)alloc((size_t)(n + 1) * 4);
    int* bsum = (int*)alloc(512 * 4);
    int* csr = (int*)alloc((size_t)e * 4);
    float* bufA = (float*)alloc((size_t)n * HIDW * 4);
    float* bufB = (float*)alloc((size_t)n * HIDW * 4);

    const int gN = (n + 255) / 256;   // 391
    const int gE = (e + 255) / 256;   // 6250
    const int gG = (n + 31) / 32;     // 3125 (gemm: 32 nodes/block)
    const int gV = (n + 3) / 4;       // 25000 (gather: 4 nodes/block)

    // CSR build + degree norm
    k_zero2<<<gN, 256, 0, stream>>>(deg, cur, n);
    k_count<<<gE, 256, 0, stream>>>(dstv, deg, e);
    k_scan1<<<gN, 256, 0, stream>>>(deg, roff, bsum, n);
    k_scan2<<<1, 512, 0, stream>>>(bsum, gN);
    k_scan3<<<gN, 256, 0, stream>>>(roff, bsum, n);
    k_dinv<<<gN, 256, 0, stream>>>(deg, dinv, n);
    k_fill<<<gE, 256, 0, stream>>>(srcv, dstv, roff, cur, csr, e);

    // 3 GCN layers
    for (int L = 0; L < 3; ++L) {
        if (L == 0)
            k_gemm<128><<<gG, 256, 0, stream>>>(x, W[0], bufB, n);
        else
            k_gemm<64><<<gG, 256, 0, stream>>>(bufA, W[L], bufB, n);
        k_gather<<<gV, 256, 0, stream>>>(bufB, csr, roff, deg, dinv, B[L], bufA, n);
        k_stats_zero<<<1, 128, 0, stream>>>(stats);
        k_stats_acc<<<200, 256, 0, stream>>>(bufA, stats, n);
        k_stats_fin<<<1, 64, 0, stream>>>(stats, 1.0f / (float)n);
        k_bn_relu<<<(n * HIDW + 255) / 256, 256, 0, stream>>>(bufA, stats, G[L], BT[L], n * HIDW);
    }

    // head
    k_head<<<gN, 256, 0, stream>>>(bufA, lw1, lb1, lw2, lb2, out, n);
}

// Round 4
// 720.136 us; speedup vs baseline: 1.9698x; 1.2898x over previous
//
#include <hip/hip_runtime.h>

// ---------------- constants ----------------
#define HIDW 64
#define EPSV 1e-5f

// ---------------- CSR build ----------------
__global__ __launch_bounds__(256) void k_zero2(int* __restrict__ a, int* __restrict__ b, int n) {
    int i = blockIdx.x * 256 + threadIdx.x;
    if (i < n) { a[i] = 0; b[i] = 0; }
}

__global__ __launch_bounds__(256) void k_count(const int* __restrict__ dstv, int* __restrict__ deg, int e) {
    int i = blockIdx.x * 256 + threadIdx.x;
    if (i < e) atomicAdd(&deg[dstv[i]], 1);
}

__global__ __launch_bounds__(256) void k_dinv(const int* __restrict__ deg, float* __restrict__ dinv, int n) {
    int i = blockIdx.x * 256 + threadIdx.x;
    if (i < n) dinv[i] = rsqrtf(1.0f + (float)deg[i]);
}

// exclusive scan, 3-phase (chunk=256)
__global__ __launch_bounds__(256) void k_scan1(const int* __restrict__ deg, int* __restrict__ off,
                                               int* __restrict__ bsum, int n) {
    __shared__ int s[256];
    int tid = threadIdx.x;
    int i = blockIdx.x * 256 + tid;
    int v = (i < n) ? deg[i] : 0;
    s[tid] = v;
    __syncthreads();
    for (int o = 1; o < 256; o <<= 1) {
        int t = (tid >= o) ? s[tid - o] : 0;
        __syncthreads();
        s[tid] += t;
        __syncthreads();
    }
    if (i < n) off[i] = s[tid] - v;
    if (tid == 255) bsum[blockIdx.x] = s[255];
}

__global__ __launch_bounds__(512) void k_scan2(int* __restrict__ bsum, int nb) {
    __shared__ int s[512];
    int tid = threadIdx.x;
    int v = (tid < nb) ? bsum[tid] : 0;
    s[tid] = v;
    __syncthreads();
    for (int o = 1; o < 512; o <<= 1) {
        int t = (tid >= o) ? s[tid - o] : 0;
        __syncthreads();
        s[tid] += t;
        __syncthreads();
    }
    if (tid < nb) bsum[tid] = s[tid] - v;
}

__global__ __launch_bounds__(256) void k_scan3(int* __restrict__ off, const int* __restrict__ bsum, int n) {
    int i = blockIdx.x * 256 + threadIdx.x;
    if (i < n) off[i] += bsum[blockIdx.x];
}

__global__ __launch_bounds__(256) void k_fill(const int* __restrict__ srcv, const int* __restrict__ dstv,
                                              const int* __restrict__ off, int* __restrict__ cur,
                                              int* __restrict__ csr, int e) {
    int i = blockIdx.x * 256 + threadIdx.x;
    if (i < e) {
        int d = dstv[i];
        int p = off[d] + atomicAdd(&cur[d], 1);
        csr[p] = srcv[i];
    }
}

// ---------------- GEMM: hw[N,64] = h[N,K] @ W[K,64] ----------------
// 64-node tile per 256-thread block. h tile staged in LDS (padded stride K+4,
// coalesced float4 loads), W natural [k][fo]. Thread (tx,ny) computes a
// 4-node x 4-output register block; per k-quad: 8 ds_read_b128 (~96 cyc) vs
// 64 FMA-instr (128 cyc) per wave -> VALU-bound. Round-3 version was
// latency-bound (VALUBusy 26%) on wave-uniform broadcast h loads.
template <int K>
__global__ __launch_bounds__(256) void k_gemm(const float* __restrict__ h, const float* __restrict__ W,
                                              float* __restrict__ hw, int n) {
    constexpr int KP = K + 4;       // padded row stride (floats), 16B aligned
    constexpr int KQ = K / 4;       // float4s per row
    __shared__ float sH[64 * KP];
    __shared__ float sW[K * 64];
    int tid = threadIdx.x;
    int node0 = blockIdx.x * 64;

    // stage W (coalesced float4)
    for (int i = tid; i < K * 16; i += 256)
        ((float4*)sW)[i] = ((const float4*)W)[i];
    // stage h tile (coalesced float4, rows padded)
    for (int i = tid; i < 64 * KQ; i += 256) {
        int row = i / KQ, kq = i % KQ;
        int nn = node0 + row;
        if (nn >= n) nn = n - 1;
        float4 v = ((const float4*)h)[(size_t)nn * KQ + kq];
        ((float4*)(sH + row * KP))[kq] = v;
    }
    __syncthreads();

    int tx = tid & 15;      // output group: channels 4tx..4tx+3
    int ny = tid >> 4;      // node group: nodes 4ny..4ny+3
    const float* hbase = sH + (4 * ny) * KP;

    float acc[4][4];
#pragma unroll
    for (int j = 0; j < 4; ++j)
#pragma unroll
        for (int c = 0; c < 4; ++c) acc[j][c] = 0.f;

#pragma unroll 2
    for (int kq = 0; kq < KQ; ++kq) {
        float4 w0 = ((const float4*)(sW + (4 * kq + 0) * 64))[tx];
        float4 w1 = ((const float4*)(sW + (4 * kq + 1) * 64))[tx];
        float4 w2 = ((const float4*)(sW + (4 * kq + 2) * 64))[tx];
        float4 w3 = ((const float4*)(sW + (4 * kq + 3) * 64))[tx];
#pragma unroll
        for (int j = 0; j < 4; ++j) {
            float4 hv = ((const float4*)(hbase + j * KP))[kq];
            acc[j][0] = fmaf(hv.x, w0.x, acc[j][0]);
            acc[j][1] = fmaf(hv.x, w0.y, acc[j][1]);
            acc[j][2] = fmaf(hv.x, w0.z, acc[j][2]);
            acc[j][3] = fmaf(hv.x, w0.w, acc[j][3]);
            acc[j][0] = fmaf(hv.y, w1.x, acc[j][0]);
            acc[j][1] = fmaf(hv.y, w1.y, acc[j][1]);
            acc[j][2] = fmaf(hv.y, w1.z, acc[j][2]);
            acc[j][3] = fmaf(hv.y, w1.w, acc[j][3]);
            acc[j][0] = fmaf(hv.z, w2.x, acc[j][0]);
            acc[j][1] = fmaf(hv.z, w2.y, acc[j][1]);
            acc[j][2] = fmaf(hv.z, w2.z, acc[j][2]);
            acc[j][3] = fmaf(hv.z, w2.w, acc[j][3]);
            acc[j][0] = fmaf(hv.w, w3.x, acc[j][0]);
            acc[j][1] = fmaf(hv.w, w3.y, acc[j][1]);
            acc[j][2] = fmaf(hv.w, w3.z, acc[j][2]);
            acc[j][3] = fmaf(hv.w, w3.w, acc[j][3]);
        }
    }

#pragma unroll
    for (int j = 0; j < 4; ++j) {
        int node = node0 + 4 * ny + j;
        if (node < n) {
            float4 r;
            r.x = acc[j][0]; r.y = acc[j][1]; r.z = acc[j][2]; r.w = acc[j][3];
            ((float4*)hw)[(size_t)node * 16 + tx] = r;
        }
    }
}

// ---------------- gather-aggregate ----------------
// one wave per node; lane = 16*g + c4: 4 neighbor-groups (g) x 16 lanes x float4
// channels. Each global_load_dwordx4 fetches 4 edges' worth (1 KB useful/wave
// vs 256B in round-3 layout) -> 4x fewer VMEM issues on a latency-bound loop.
// Cross-lane shfl_xor(16,32) reduce combines the 4 groups.
__global__ __launch_bounds__(256) void k_gather(const float* __restrict__ hw, const int* __restrict__ csr,
                                                const int* __restrict__ off, const int* __restrict__ deg,
                                                const float* __restrict__ dinv, const float* __restrict__ bias,
                                                float* __restrict__ agg, int n) {
    int tid = threadIdx.x;
    int lane = tid & 63;
    int v = blockIdx.x * 4 + (tid >> 6);
    if (v >= n) return;
    int g = lane >> 4;
    int c4 = lane & 15;
    float dv = dinv[v];
    const float4* hw4 = (const float4*)hw;

    float4 acc = make_float4(0.f, 0.f, 0.f, 0.f);
    if (g == 0) {  // self loop
        float4 s = hw4[(size_t)v * 16 + c4];
        float w = dv * dv;
        acc.x = s.x * w; acc.y = s.y * w; acc.z = s.z * w; acc.w = s.w * w;
    }
    int s0 = off[v];
    int cnt = deg[v];
#pragma unroll 2
    for (int i = g; i < cnt; i += 4) {
        int a = csr[s0 + i];
        float w = dinv[a] * dv;
        float4 hv = hw4[(size_t)a * 16 + c4];
        acc.x = fmaf(hv.x, w, acc.x);
        acc.y = fmaf(hv.y, w, acc.y);
        acc.z = fmaf(hv.z, w, acc.z);
        acc.w = fmaf(hv.w, w, acc.w);
    }
    // reduce across the 4 neighbor-groups (lanes 16 apart)
    acc.x += __shfl_xor(acc.x, 16);
    acc.y += __shfl_xor(acc.y, 16);
    acc.z += __shfl_xor(acc.z, 16);
    acc.w += __shfl_xor(acc.w, 16);
    acc.x += __shfl_xor(acc.x, 32);
    acc.y += __shfl_xor(acc.y, 32);
    acc.z += __shfl_xor(acc.z, 32);
    acc.w += __shfl_xor(acc.w, 32);
    if (lane < 16) {
        float4 b = ((const float4*)bias)[c4];
        acc.x += b.x; acc.y += b.y; acc.z += b.z; acc.w += b.w;
        ((float4*)agg)[(size_t)v * 16 + c4] = acc;
    }
}

// ---------------- BatchNorm (training-mode batch stats) + ReLU ----------------
__global__ void k_stats_zero(float* __restrict__ st) {
    int i = threadIdx.x;
    if (i < 128) st[i] = 0.f;
}

__global__ __launch_bounds__(256) void k_stats_acc(const float* __restrict__ a, float* __restrict__ st, int n) {
    __shared__ float ss[256];
    __shared__ float sq[256];
    int tid = threadIdx.x;
    int c = tid & 63;
    int r = tid >> 6;
    float s = 0.f, q = 0.f;
    for (int nd = blockIdx.x * 4 + r; nd < n; nd += gridDim.x * 4) {
        float v = a[(size_t)nd * HIDW + c];
        s += v;
        q += v * v;
    }
    ss[tid] = s;
    sq[tid] = q;
    __syncthreads();
    if (tid < 64) {
        float S = ss[tid] + ss[tid + 64] + ss[tid + 128] + ss[tid + 192];
        float Q = sq[tid] + sq[tid + 64] + sq[tid + 128] + sq[tid + 192];
        atomicAdd(&st[c], S);
        atomicAdd(&st[64 + c], Q);
    }
}

__global__ void k_stats_fin(float* __restrict__ st, float invn) {
    int c = threadIdx.x;
    if (c < 64) {
        float mu = st[c] * invn;
        float var = st[64 + c] * invn - mu * mu;
        var = fmaxf(var, 0.f);
        st[c] = mu;
        st[64 + c] = rsqrtf(var + EPSV);
    }
}

__global__ __launch_bounds__(256) void k_bn_relu(float* __restrict__ a, const float* __restrict__ st,
                                                 const float* __restrict__ g, const float* __restrict__ bt,
                                                 int total) {
    int i = blockIdx.x * 256 + threadIdx.x;
    if (i < total) {
        int c = i & 63;
        float y = (a[i] - st[c]) * st[64 + c] * g[c] + bt[c];
        a[i] = fmaxf(y, 0.f);
    }
}

// ---------------- MLP head: out = relu(h@lw1+lb1)@lw2+lb2 ----------------
__global__ __launch_bounds__(256) void k_head(const float* __restrict__ h, const float* __restrict__ lw1,
                                              const float* __restrict__ lb1, const float* __restrict__ lw2,
                                              const float* __restrict__ lb2, float* __restrict__ out, int n) {
    __shared__ float sW[64 * 32];
    __shared__ float sb1[32];
    __shared__ float sw2[32];
    int tid = threadIdx.x;
    for (int i = tid; i < 64 * 32; i += 256) sW[i] = lw1[i];
    if (tid < 32) {
        sb1[tid] = lb1[tid];
        sw2[tid] = lw2[tid];
    }
    __syncthreads();
    int nd = blockIdx.x * 256 + tid;
    if (nd >= n) return;
    float acc[32];
#pragma unroll
    for (int j = 0; j < 32; ++j) acc[j] = sb1[j];
    const float4* hr = (const float4*)(h + (size_t)nd * HIDW);
#pragma unroll 4
    for (int kc = 0; kc < 16; ++kc) {
        float4 h4 = hr[kc];
        const float* w0 = &sW[(kc * 4 + 0) * 32];
        const float* w1 = &sW[(kc * 4 + 1) * 32];
        const float* w2 = &sW[(kc * 4 + 2) * 32];
        const float* w3 = &sW[(kc * 4 + 3) * 32];
#pragma unroll
        for (int j = 0; j < 32; ++j) {
            float t = fmaf(h4.x, w0[j], fmaf(h4.y, w1[j], fmaf(h4.z, w2[j], h4.w * w3[j])));
            acc[j] += t;
        }
    }
    float o = lb2[0];
#pragma unroll
    for (int j = 0; j < 32; ++j) o = fmaf(fmaxf(acc[j], 0.f), sw2[j], o);
    out[nd] = o;
}

// ---------------- launch ----------------
extern "C" void kernel_launch(void* const* d_in, const int* in_sizes, int n_in,
                              void* d_out, int out_size, void* d_ws, size_t ws_size,
                              hipStream_t stream) {
    const float* x = (const float*)d_in[0];
    const int* ei = (const int*)d_in[1];
    const float* W[3] = {(const float*)d_in[2], (const float*)d_in[6], (const float*)d_in[10]};
    const float* B[3] = {(const float*)d_in[3], (const float*)d_in[7], (const float*)d_in[11]};
    const float* G[3] = {(const float*)d_in[4], (const float*)d_in[8], (const float*)d_in[12]};
    const float* BT[3] = {(const float*)d_in[5], (const float*)d_in[9], (const float*)d_in[13]};
    const float* lw1 = (const float*)d_in[14];
    const float* lb1 = (const float*)d_in[15];
    const float* lw2 = (const float*)d_in[16];
    const float* lb2 = (const float*)d_in[17];
    float* out = (float*)d_out;

    const int n = in_sizes[0] / 128;  // 100000
    const int e = in_sizes[1] / 2;    // 1600000
    const int* srcv = ei;
    const int* dstv = ei + e;

    // workspace carve-up (all fully re-initialized every call)
    char* ws = (char*)d_ws;
    size_t off = 0;
    auto alloc = [&](size_t bytes) -> char* {
        off = (off + 511) & ~(size_t)511;
        char* p = ws + off;
        off += bytes;
        return p;
    };
    float* stats = (float*)alloc(512);
    float* dinv = (float*)alloc((size_t)n * 4);
    int* deg = (int*)alloc((size_t)n * 4);
    int* cur = (int*)alloc((size_t)n * 4);
    int* roff = (int*)alloc((size_t)(n + 1) * 4);
    int* bsum = (int*)alloc(512 * 4);
    int* csr = (int*)alloc((size_t)e * 4);
    float* bufA = (float*)alloc((size_t)n * HIDW * 4);
    float* bufB = (float*)alloc((size_t)n * HIDW * 4);

    const int gN = (n + 255) / 256;   // 391
    const int gE = (e + 255) / 256;   // 6250
    const int gG = (n + 63) / 64;     // 1563 (gemm: 64 nodes/block)
    const int gV = (n + 3) / 4;       // 25000 (gather: 4 nodes/block)

    // CSR build + degree norm
    k_zero2<<<gN, 256, 0, stream>>>(deg, cur, n);
    k_count<<<gE, 256, 0, stream>>>(dstv, deg, e);
    k_scan1<<<gN, 256, 0, stream>>>(deg, roff, bsum, n);
    k_scan2<<<1, 512, 0, stream>>>(bsum, gN);
    k_scan3<<<gN, 256, 0, stream>>>(roff, bsum, n);
    k_dinv<<<gN, 256, 0, stream>>>(deg, dinv, n);
    k_fill<<<gE, 256, 0, stream>>>(srcv, dstv, roff, cur, csr, e);

    // 3 GCN layers
    for (int L = 0; L < 3; ++L) {
        if (L == 0)
            k_gemm<128><<<gG, 256, 0, stream>>>(x, W[0], bufB, n);
        else
            k_gemm<64><<<gG, 256, 0, stream>>>(bufA, W[L], bufB, n);
        k_gather<<<gV, 256, 0, stream>>>(bufB, csr, roff, deg, dinv, B[L], bufA, n);
        k_stats_zero<<<1, 128, 0, stream>>>(stats);
        k_stats_acc<<<200, 256, 0, stream>>>(bufA, stats, n);
        k_stats_fin<<<1, 64, 0, stream>>>(stats, 1.0f / (float)n);
        k_bn_relu<<<(n * HIDW + 255) / 256, 256, 0, stream>>>(bufA, stats, G[L], BT[L], n * HIDW);
    }

    // head
    k_head<<<gN, 256, 0, stream>>>(bufA, lw1, lb1, lw2, lb2, out, n);
}

// Round 5
// 673.999 us; speedup vs baseline: 2.1046x; 1.0685x over previous
//
#include <hip/hip_runtime.h>

// ---------------- constants ----------------
#define HIDW 64
#define EPSV 1e-5f
#define CAP 32   // bucket capacity; Poisson(16) P(deg>32) ~ 2e-5 -> overflow path

// ---------------- init: zero deg / flags / ovfcnt ----------------
__global__ __launch_bounds__(256) void k_zero(int* __restrict__ deg, unsigned int* __restrict__ flags,
                                              int* __restrict__ ovfcnt, int n, int nf) {
    int i = blockIdx.x * 256 + threadIdx.x;
    if (i < n) deg[i] = 0;
    if (i < nf) flags[i] = 0u;
    if (i == 0) ovfcnt[0] = 0;
}

// ---------------- path A: fused count+fill into fixed-capacity buckets ----------------
__global__ __launch_bounds__(256) void k_build(const int* __restrict__ srcv, const int* __restrict__ dstv,
                                               int* __restrict__ deg, int* __restrict__ csr,
                                               unsigned int* __restrict__ flags, int* __restrict__ ovfcnt, int e) {
    int i = blockIdx.x * 256 + threadIdx.x;
    if (i >= e) return;
    int d = dstv[i];
    int slot = atomicAdd(&deg[d], 1);
    if (slot < CAP) {
        csr[(size_t)d * CAP + slot] = srcv[i];
    } else {
        atomicOr(&flags[i >> 5], 1u << (i & 31));
        atomicAdd(ovfcnt, 1);
    }
}

// overflow edges (expected ~0): applied after gather, before BN stats
__global__ __launch_bounds__(256) void k_ovf(const float* __restrict__ hw, const int* __restrict__ srcv,
                                             const int* __restrict__ dstv, const unsigned int* __restrict__ flags,
                                             const int* __restrict__ ovfcnt, const float* __restrict__ dinv,
                                             float* __restrict__ agg, int e) {
    if (ovfcnt[0] == 0) return;
    int nw = (e + 31) >> 5;
    for (int w = blockIdx.x * 256 + threadIdx.x; w < nw; w += gridDim.x * 256) {
        unsigned int f = flags[w];
        while (f) {
            int b = __ffs(f) - 1;
            f &= f - 1;
            int i = w * 32 + b;
            int s = srcv[i], d = dstv[i];
            float wt = dinv[s] * dinv[d];
            for (int c = 0; c < HIDW; ++c)
                atomicAdd(&agg[(size_t)d * HIDW + c], hw[(size_t)s * HIDW + c] * wt);
        }
    }
}

__global__ __launch_bounds__(256) void k_dinv(const int* __restrict__ deg, float* __restrict__ dinv, int n) {
    int i = blockIdx.x * 256 + threadIdx.x;
    if (i < n) dinv[i] = rsqrtf(1.0f + (float)deg[i]);
}

// ---------------- path B (fallback, classic 2-pass CSR) ----------------
__global__ __launch_bounds__(256) void k_count(const int* __restrict__ dstv, int* __restrict__ deg, int e) {
    int i = blockIdx.x * 256 + threadIdx.x;
    if (i < e) atomicAdd(&deg[dstv[i]], 1);
}

__global__ __launch_bounds__(256) void k_scan1(const int* __restrict__ deg, int* __restrict__ off,
                                               int* __restrict__ bsum, int n) {
    __shared__ int s[256];
    int tid = threadIdx.x;
    int i = blockIdx.x * 256 + tid;
    int v = (i < n) ? deg[i] : 0;
    s[tid] = v;
    __syncthreads();
    for (int o = 1; o < 256; o <<= 1) {
        int t = (tid >= o) ? s[tid - o] : 0;
        __syncthreads();
        s[tid] += t;
        __syncthreads();
    }
    if (i < n) off[i] = s[tid] - v;
    if (tid == 255) bsum[blockIdx.x] = s[255];
}

__global__ __launch_bounds__(512) void k_scan2(int* __restrict__ bsum, int nb) {
    __shared__ int s[512];
    int tid = threadIdx.x;
    int v = (tid < nb) ? bsum[tid] : 0;
    s[tid] = v;
    __syncthreads();
    for (int o = 1; o < 512; o <<= 1) {
        int t = (tid >= o) ? s[tid - o] : 0;
        __syncthreads();
        s[tid] += t;
        __syncthreads();
    }
    if (tid < nb) bsum[tid] = s[tid] - v;
}

__global__ __launch_bounds__(256) void k_scan3(int* __restrict__ off, const int* __restrict__ bsum, int n) {
    int i = blockIdx.x * 256 + threadIdx.x;
    if (i < n) off[i] += bsum[blockIdx.x];
}

// fill via roff post-increment (roff becomes END offsets; start = roff[v]-deg[v])
__global__ __launch_bounds__(256) void k_fill2(const int* __restrict__ srcv, const int* __restrict__ dstv,
                                               int* __restrict__ roff, int* __restrict__ csr, int e) {
    int i = blockIdx.x * 256 + threadIdx.x;
    if (i < e) {
        int d = dstv[i];
        int p = atomicAdd(&roff[d], 1);
        csr[p] = srcv[i];
    }
}

// ---------------- GEMM: hw[N,64] = h[N,K] @ W[K,64] (round-4 tiled, VALU-bound) ----------------
template <int K>
__global__ __launch_bounds__(256) void k_gemm(const float* __restrict__ h, const float* __restrict__ W,
                                              float* __restrict__ hw, int n) {
    constexpr int KP = K + 4;
    constexpr int KQ = K / 4;
    __shared__ float sH[64 * KP];
    __shared__ float sW[K * 64];
    int tid = threadIdx.x;
    int node0 = blockIdx.x * 64;

    for (int i = tid; i < K * 16; i += 256)
        ((float4*)sW)[i] = ((const float4*)W)[i];
    for (int i = tid; i < 64 * KQ; i += 256) {
        int row = i / KQ, kq = i % KQ;
        int nn = node0 + row;
        if (nn >= n) nn = n - 1;
        float4 v = ((const float4*)h)[(size_t)nn * KQ + kq];
        ((float4*)(sH + row * KP))[kq] = v;
    }
    __syncthreads();

    int tx = tid & 15;
    int ny = tid >> 4;
    const float* hbase = sH + (4 * ny) * KP;

    float acc[4][4];
#pragma unroll
    for (int j = 0; j < 4; ++j)
#pragma unroll
        for (int c = 0; c < 4; ++c) acc[j][c] = 0.f;

#pragma unroll 2
    for (int kq = 0; kq < KQ; ++kq) {
        float4 w0 = ((const float4*)(sW + (4 * kq + 0) * 64))[tx];
        float4 w1 = ((const float4*)(sW + (4 * kq + 1) * 64))[tx];
        float4 w2 = ((const float4*)(sW + (4 * kq + 2) * 64))[tx];
        float4 w3 = ((const float4*)(sW + (4 * kq + 3) * 64))[tx];
#pragma unroll
        for (int j = 0; j < 4; ++j) {
            float4 hv = ((const float4*)(hbase + j * KP))[kq];
            acc[j][0] = fmaf(hv.x, w0.x, acc[j][0]);
            acc[j][1] = fmaf(hv.x, w0.y, acc[j][1]);
            acc[j][2] = fmaf(hv.x, w0.z, acc[j][2]);
            acc[j][3] = fmaf(hv.x, w0.w, acc[j][3]);
            acc[j][0] = fmaf(hv.y, w1.x, acc[j][0]);
            acc[j][1] = fmaf(hv.y, w1.y, acc[j][1]);
            acc[j][2] = fmaf(hv.y, w1.z, acc[j][2]);
            acc[j][3] = fmaf(hv.y, w1.w, acc[j][3]);
            acc[j][0] = fmaf(hv.z, w2.x, acc[j][0]);
            acc[j][1] = fmaf(hv.z, w2.y, acc[j][1]);
            acc[j][2] = fmaf(hv.z, w2.z, acc[j][2]);
            acc[j][3] = fmaf(hv.z, w2.w, acc[j][3]);
            acc[j][0] = fmaf(hv.w, w3.x, acc[j][0]);
            acc[j][1] = fmaf(hv.w, w3.y, acc[j][1]);
            acc[j][2] = fmaf(hv.w, w3.z, acc[j][2]);
            acc[j][3] = fmaf(hv.w, w3.w, acc[j][3]);
        }
    }

#pragma unroll
    for (int j = 0; j < 4; ++j) {
        int node = node0 + 4 * ny + j;
        if (node < n) {
            float4 r;
            r.x = acc[j][0]; r.y = acc[j][1]; r.z = acc[j][2]; r.w = acc[j][3];
            ((float4*)hw)[(size_t)node * 16 + tx] = r;
        }
    }
}

// ---------------- gather: wave per node, wave-uniform edge processing ----------------
// Preload <=64 neighbor indices+weights coalesced into lanes; shfl each to the
// whole wave -> per edge ONE coalesced 256B row load from a uniform base, 4
// independent loads in flight. Round-4 had a dependent csr->row chain per group.
template <bool BUCKET>
__global__ __launch_bounds__(256) void k_gather(const float* __restrict__ hw, const int* __restrict__ csr,
                                                const int* __restrict__ roff, const int* __restrict__ deg,
                                                const float* __restrict__ dinv, const float* __restrict__ bias,
                                                float* __restrict__ agg, int n) {
    int tid = threadIdx.x;
    int lane = tid & 63;
    int v = blockIdx.x * 4 + (tid >> 6);
    if (v >= n) return;
    int dcnt = deg[v];
    float dv = dinv[v];
    int cnt;
    const int* base;
    if (BUCKET) {
        cnt = min(dcnt, CAP);
        base = csr + (size_t)v * CAP;
    } else {
        cnt = dcnt;
        base = csr + (roff[v] - dcnt);  // roff holds end offsets after k_fill2
    }
    float acc = bias[lane] + hw[(size_t)v * HIDW + lane] * dv * dv;
    for (int j0 = 0; j0 < cnt; j0 += 64) {
        int m = min(cnt - j0, 64);
        int idx = (lane < m) ? base[j0 + lane] : 0;
        float wl = (lane < m) ? dinv[idx] * dv : 0.f;
        int j = 0;
        for (; j + 4 <= m; j += 4) {
            int a0 = __shfl(idx, j + 0); float w0 = __shfl(wl, j + 0);
            int a1 = __shfl(idx, j + 1); float w1 = __shfl(wl, j + 1);
            int a2 = __shfl(idx, j + 2); float w2 = __shfl(wl, j + 2);
            int a3 = __shfl(idx, j + 3); float w3 = __shfl(wl, j + 3);
            float f0 = hw[(size_t)a0 * HIDW + lane];
            float f1 = hw[(size_t)a1 * HIDW + lane];
            float f2 = hw[(size_t)a2 * HIDW + lane];
            float f3 = hw[(size_t)a3 * HIDW + lane];
            acc = fmaf(f0, w0, acc);
            acc = fmaf(f1, w1, acc);
            acc = fmaf(f2, w2, acc);
            acc = fmaf(f3, w3, acc);
        }
        for (; j < m; ++j) {
            int a = __shfl(idx, j);
            float w = __shfl(wl, j);
            acc = fmaf(hw[(size_t)a * HIDW + lane], w, acc);
        }
    }
    agg[(size_t)v * HIDW + lane] = acc;
}

// ---------------- BatchNorm (training-mode batch stats) + ReLU ----------------
__global__ void k_stats_zero(float* __restrict__ st) {
    int i = threadIdx.x;
    if (i < 128) st[i] = 0.f;
}

__global__ __launch_bounds__(256) void k_stats_acc(const float* __restrict__ a, float* __restrict__ st, int n) {
    __shared__ float ss[256];
    __shared__ float sq[256];
    int tid = threadIdx.x;
    int c = tid & 63;
    int r = tid >> 6;
    float s = 0.f, q = 0.f;
    for (int nd = blockIdx.x * 4 + r; nd < n; nd += gridDim.x * 4) {
        float v = a[(size_t)nd * HIDW + c];
        s += v;
        q += v * v;
    }
    ss[tid] = s;
    sq[tid] = q;
    __syncthreads();
    if (tid < 64) {
        float S = ss[tid] + ss[tid + 64] + ss[tid + 128] + ss[tid + 192];
        float Q = sq[tid] + sq[tid + 64] + sq[tid + 128] + sq[tid + 192];
        atomicAdd(&st[c], S);
        atomicAdd(&st[64 + c], Q);
    }
}

__global__ void k_stats_fin(float* __restrict__ st, float invn) {
    int c = threadIdx.x;
    if (c < 64) {
        float mu = st[c] * invn;
        float var = st[64 + c] * invn - mu * mu;
        var = fmaxf(var, 0.f);
        st[c] = mu;
        st[64 + c] = rsqrtf(var + EPSV);
    }
}

__global__ __launch_bounds__(256) void k_bn_relu(float* __restrict__ a, const float* __restrict__ st,
                                                 const float* __restrict__ g, const float* __restrict__ bt,
                                                 int total) {
    int i = blockIdx.x * 256 + threadIdx.x;
    if (i < total) {
        int c = i & 63;
        float y = (a[i] - st[c]) * st[64 + c] * g[c] + bt[c];
        a[i] = fmaxf(y, 0.f);
    }
}

// ---------------- MLP head ----------------
__global__ __launch_bounds__(256) void k_head(const float* __restrict__ h, const float* __restrict__ lw1,
                                              const float* __restrict__ lb1, const float* __restrict__ lw2,
                                              const float* __restrict__ lb2, float* __restrict__ out, int n) {
    __shared__ float sW[64 * 32];
    __shared__ float sb1[32];
    __shared__ float sw2[32];
    int tid = threadIdx.x;
    for (int i = tid; i < 64 * 32; i += 256) sW[i] = lw1[i];
    if (tid < 32) {
        sb1[tid] = lb1[tid];
        sw2[tid] = lw2[tid];
    }
    __syncthreads();
    int nd = blockIdx.x * 256 + tid;
    if (nd >= n) return;
    float acc[32];
#pragma unroll
    for (int j = 0; j < 32; ++j) acc[j] = sb1[j];
    const float4* hr = (const float4*)(h + (size_t)nd * HIDW);
#pragma unroll 4
    for (int kc = 0; kc < 16; ++kc) {
        float4 h4 = hr[kc];
        const float* w0 = &sW[(kc * 4 + 0) * 32];
        const float* w1 = &sW[(kc * 4 + 1) * 32];
        const float* w2 = &sW[(kc * 4 + 2) * 32];
        const float* w3 = &sW[(kc * 4 + 3) * 32];
#pragma unroll
        for (int j = 0; j < 32; ++j) {
            float t = fmaf(h4.x, w0[j], fmaf(h4.y, w1[j], fmaf(h4.z, w2[j], h4.w * w3[j])));
            acc[j] += t;
        }
    }
    float o = lb2[0];
#pragma unroll
    for (int j = 0; j < 32; ++j) o = fmaf(fmaxf(acc[j], 0.f), sw2[j], o);
    out[nd] = o;
}

// ---------------- launch ----------------
extern "C" void kernel_launch(void* const* d_in, const int* in_sizes, int n_in,
                              void* d_out, int out_size, void* d_ws, size_t ws_size,
                              hipStream_t stream) {
    const float* x = (const float*)d_in[0];
    const int* ei = (const int*)d_in[1];
    const float* W[3] = {(const float*)d_in[2], (const float*)d_in[6], (const float*)d_in[10]};
    const float* B[3] = {(const float*)d_in[3], (const float*)d_in[7], (const float*)d_in[11]};
    const float* G[3] = {(const float*)d_in[4], (const float*)d_in[8], (const float*)d_in[12]};
    const float* BT[3] = {(const float*)d_in[5], (const float*)d_in[9], (const float*)d_in[13]};
    const float* lw1 = (const float*)d_in[14];
    const float* lb1 = (const float*)d_in[15];
    const float* lw2 = (const float*)d_in[16];
    const float* lb2 = (const float*)d_in[17];
    float* out = (float*)d_out;

    const int n = in_sizes[0] / 128;  // 100000
    const int e = in_sizes[1] / 2;    // 1600000
    const int* srcv = ei;
    const int* dstv = ei + e;
    const int nf = (e + 31) / 32;     // flag words

    char* ws = (char*)d_ws;
    size_t off = 0;
    auto alloc = [&](size_t bytes) -> char* {
        off = (off + 511) & ~(size_t)511;
        char* p = ws + off;
        off += bytes;
        return p;
    };
    // common
    float* stats = (float*)alloc(512);
    int* ovfcnt = (int*)alloc(512);
    float* dinv = (float*)alloc((size_t)n * 4);
    int* deg = (int*)alloc((size_t)n * 4);
    float* bufA = (float*)alloc((size_t)n * HIDW * 4);
    float* bufB = (float*)alloc((size_t)n * HIDW * 4);
    size_t commonOff = off;

    // path A sizing: flags + bucket csr
    size_t needA = ((commonOff + 511) & ~(size_t)511) + (size_t)nf * 4;
    needA = ((needA + 511) & ~(size_t)511) + (size_t)n * CAP * 4;
    bool useA = (needA <= ws_size);

    const int gN = (n + 255) / 256;   // 391
    const int gE = (e + 255) / 256;   // 6250
    const int gG = (n + 63) / 64;     // 1563
    const int gV = (n + 3) / 4;       // 25000

    unsigned int* flags = nullptr;
    int* csrB = nullptr;   // bucket csr (path A)
    int* roff = nullptr;
    int* bsum = nullptr;
    int* csrC = nullptr;   // contiguous csr (path B)

    if (useA) {
        flags = (unsigned int*)alloc((size_t)nf * 4);
        csrB = (int*)alloc((size_t)n * CAP * 4);
        k_zero<<<gN, 256, 0, stream>>>(deg, flags, ovfcnt, n, nf);
        k_build<<<gE, 256, 0, stream>>>(srcv, dstv, deg, csrB, flags, ovfcnt, e);
        k_dinv<<<gN, 256, 0, stream>>>(deg, dinv, n);
    } else {
        roff = (int*)alloc((size_t)(n + 1) * 4);
        bsum = (int*)alloc(512 * 4);
        csrC = (int*)alloc((size_t)e * 4);
        k_zero<<<gN, 256, 0, stream>>>(deg, (unsigned int*)bsum, ovfcnt, n, 0);
        k_count<<<gE, 256, 0, stream>>>(dstv, deg, e);
        k_scan1<<<gN, 256, 0, stream>>>(deg, roff, bsum, n);
        k_scan2<<<1, 512, 0, stream>>>(bsum, gN);
        k_scan3<<<gN, 256, 0, stream>>>(roff, bsum, n);
        k_dinv<<<gN, 256, 0, stream>>>(deg, dinv, n);
        k_fill2<<<gE, 256, 0, stream>>>(srcv, dstv, roff, csrC, e);
    }

    for (int L = 0; L < 3; ++L) {
        if (L == 0)
            k_gemm<128><<<gG, 256, 0, stream>>>(x, W[0], bufB, n);
        else
            k_gemm<64><<<gG, 256, 0, stream>>>(bufA, W[L], bufB, n);
        if (useA) {
            k_gather<true><<<gV, 256, 0, stream>>>(bufB, csrB, nullptr, deg, dinv, B[L], bufA, n);
            k_ovf<<<256, 256, 0, stream>>>(bufB, srcv, dstv, flags, ovfcnt, dinv, bufA, e);
        } else {
            k_gather<false><<<gV, 256, 0, stream>>>(bufB, csrC, roff, deg, dinv, B[L], bufA, n);
        }
        k_stats_zero<<<1, 128, 0, stream>>>(stats);
        k_stats_acc<<<200, 256, 0, stream>>>(bufA, stats, n);
        k_stats_fin<<<1, 64, 0, stream>>>(stats, 1.0f / (float)n);
        k_bn_relu<<<(n * HIDW + 255) / 256, 256, 0, stream>>>(bufA, stats, G[L], BT[L], n * HIDW);
    }

    k_head<<<gN, 256, 0, stream>>>(bufA, lw1, lb1, lw2, lb2, out, n);
}

// Round 6
// 584.767 us; speedup vs baseline: 2.4258x; 1.1526x over previous
//
#include <hip/hip_runtime.h>
#include <hip/hip_fp16.h>

// ---------------- constants ----------------
#define HIDW 64
#define EPSV 1e-5f
#define CAP 32     // bucket capacity; Poisson(16) P(deg>32) ~ 2e-5 -> overflow path
#define NPART 8    // XCD partitions for build locality

// ---------------- init: zero deg / flags / ovfcnt ----------------
__global__ __launch_bounds__(256) void k_zero(int* __restrict__ deg, unsigned int* __restrict__ flags,
                                              int* __restrict__ ovfcnt, int n, int nf) {
    int i = blockIdx.x * 256 + threadIdx.x;
    if (i < n) deg[i] = 0;
    if (i < nf) flags[i] = 0u;
    if (i == 0) ovfcnt[0] = 0;
}

// ---------------- path A: fused count+fill, XCD-partitioned by dst range ----------------
// Block b: edge chunk b>>3, partition b&7. Edge processed iff (d>>10)&7 == part.
// With round-robin blockIdx->XCD mapping each bucket/deg line is owned by ONE
// XCD L2 -> writeback ~unique lines (~15 MB) instead of 8x line bounce (96 MB).
__global__ __launch_bounds__(256) void k_build(const int* __restrict__ srcv, const int* __restrict__ dstv,
                                               int* __restrict__ deg, int* __restrict__ csr,
                                               unsigned int* __restrict__ flags, int* __restrict__ ovfcnt, int e) {
    int part = blockIdx.x & (NPART - 1);
    int i = (blockIdx.x >> 3) * 256 + threadIdx.x;
    if (i >= e) return;
    int d = dstv[i];
    if (((d >> 10) & (NPART - 1)) != part) return;
    int slot = atomicAdd(&deg[d], 1);
    if (slot < CAP) {
        csr[(size_t)d * CAP + slot] = srcv[i];
    } else {
        atomicOr(&flags[i >> 5], 1u << (i & 31));
        atomicAdd(ovfcnt, 1);
    }
}

// overflow edges (expected ~0): applied after gather, before BN stats
__global__ __launch_bounds__(256) void k_ovf(const __half* __restrict__ hw, const int* __restrict__ srcv,
                                             const int* __restrict__ dstv, const unsigned int* __restrict__ flags,
                                             const int* __restrict__ ovfcnt, const float* __restrict__ dinv,
                                             float* __restrict__ agg, int e) {
    if (ovfcnt[0] == 0) return;
    int nw = (e + 31) >> 5;
    for (int w = blockIdx.x * 256 + threadIdx.x; w < nw; w += gridDim.x * 256) {
        unsigned int f = flags[w];
        while (f) {
            int b = __ffs(f) - 1;
            f &= f - 1;
            int i = w * 32 + b;
            int s = srcv[i], d = dstv[i];
            float wt = dinv[s] * dinv[d];
            for (int c = 0; c < HIDW; ++c)
                atomicAdd(&agg[(size_t)d * HIDW + c], __half2float(hw[(size_t)s * HIDW + c]) * wt);
        }
    }
}

__global__ __launch_bounds__(256) void k_dinv(const int* __restrict__ deg, float* __restrict__ dinv, int n) {
    int i = blockIdx.x * 256 + threadIdx.x;
    if (i < n) dinv[i] = rsqrtf(1.0f + (float)deg[i]);
}

// ---------------- path B (fallback, classic 2-pass CSR) ----------------
__global__ __launch_bounds__(256) void k_count(const int* __restrict__ dstv, int* __restrict__ deg, int e) {
    int i = blockIdx.x * 256 + threadIdx.x;
    if (i < e) atomicAdd(&deg[dstv[i]], 1);
}

__global__ __launch_bounds__(256) void k_scan1(const int* __restrict__ deg, int* __restrict__ off,
                                               int* __restrict__ bsum, int n) {
    __shared__ int s[256];
    int tid = threadIdx.x;
    int i = blockIdx.x * 256 + tid;
    int v = (i < n) ? deg[i] : 0;
    s[tid] = v;
    __syncthreads();
    for (int o = 1; o < 256; o <<= 1) {
        int t = (tid >= o) ? s[tid - o] : 0;
        __syncthreads();
        s[tid] += t;
        __syncthreads();
    }
    if (i < n) off[i] = s[tid] - v;
    if (tid == 255) bsum[blockIdx.x] = s[255];
}

__global__ __launch_bounds__(512) void k_scan2(int* __restrict__ bsum, int nb) {
    __shared__ int s[512];
    int tid = threadIdx.x;
    int v = (tid < nb) ? bsum[tid] : 0;
    s[tid] = v;
    __syncthreads();
    for (int o = 1; o < 512; o <<= 1) {
        int t = (tid >= o) ? s[tid - o] : 0;
        __syncthreads();
        s[tid] += t;
        __syncthreads();
    }
    if (tid < nb) bsum[tid] = s[tid] - v;
}

__global__ __launch_bounds__(256) void k_scan3(int* __restrict__ off, const int* __restrict__ bsum, int n) {
    int i = blockIdx.x * 256 + threadIdx.x;
    if (i < n) off[i] += bsum[blockIdx.x];
}

// fill via roff post-increment (roff becomes END offsets; start = roff[v]-deg[v])
__global__ __launch_bounds__(256) void k_fill2(const int* __restrict__ srcv, const int* __restrict__ dstv,
                                               int* __restrict__ roff, int* __restrict__ csr, int e) {
    int i = blockIdx.x * 256 + threadIdx.x;
    if (i < e) {
        int d = dstv[i];
        int p = atomicAdd(&roff[d], 1);
        csr[p] = srcv[i];
    }
}

// ---------------- GEMM: hw[N,64] = h[N,K] @ W[K,64], OUTPUT IN FP16 ----------------
// (round-4 tiled structure, VALU-bound; fp16 epilogue halves gather traffic)
template <int K>
__global__ __launch_bounds__(256) void k_gemm(const float* __restrict__ h, const float* __restrict__ W,
                                              __half* __restrict__ hw, int n) {
    constexpr int KP = K + 4;
    constexpr int KQ = K / 4;
    __shared__ float sH[64 * KP];
    __shared__ float sW[K * 64];
    int tid = threadIdx.x;
    int node0 = blockIdx.x * 64;

    for (int i = tid; i < K * 16; i += 256)
        ((float4*)sW)[i] = ((const float4*)W)[i];
    for (int i = tid; i < 64 * KQ; i += 256) {
        int row = i / KQ, kq = i % KQ;
        int nn = node0 + row;
        if (nn >= n) nn = n - 1;
        float4 v = ((const float4*)h)[(size_t)nn * KQ + kq];
        ((float4*)(sH + row * KP))[kq] = v;
    }
    __syncthreads();

    int tx = tid & 15;
    int ny = tid >> 4;
    const float* hbase = sH + (4 * ny) * KP;

    float acc[4][4];
#pragma unroll
    for (int j = 0; j < 4; ++j)
#pragma unroll
        for (int c = 0; c < 4; ++c) acc[j][c] = 0.f;

#pragma unroll 2
    for (int kq = 0; kq < KQ; ++kq) {
        float4 w0 = ((const float4*)(sW + (4 * kq + 0) * 64))[tx];
        float4 w1 = ((const float4*)(sW + (4 * kq + 1) * 64))[tx];
        float4 w2 = ((const float4*)(sW + (4 * kq + 2) * 64))[tx];
        float4 w3 = ((const float4*)(sW + (4 * kq + 3) * 64))[tx];
#pragma unroll
        for (int j = 0; j < 4; ++j) {
            float4 hv = ((const float4*)(hbase + j * KP))[kq];
            acc[j][0] = fmaf(hv.x, w0.x, acc[j][0]);
            acc[j][1] = fmaf(hv.x, w0.y, acc[j][1]);
            acc[j][2] = fmaf(hv.x, w0.z, acc[j][2]);
            acc[j][3] = fmaf(hv.x, w0.w, acc[j][3]);
            acc[j][0] = fmaf(hv.y, w1.x, acc[j][0]);
            acc[j][1] = fmaf(hv.y, w1.y, acc[j][1]);
            acc[j][2] = fmaf(hv.y, w1.z, acc[j][2]);
            acc[j][3] = fmaf(hv.y, w1.w, acc[j][3]);
            acc[j][0] = fmaf(hv.z, w2.x, acc[j][0]);
            acc[j][1] = fmaf(hv.z, w2.y, acc[j][1]);
            acc[j][2] = fmaf(hv.z, w2.z, acc[j][2]);
            acc[j][3] = fmaf(hv.z, w2.w, acc[j][3]);
            acc[j][0] = fmaf(hv.w, w3.x, acc[j][0]);
            acc[j][1] = fmaf(hv.w, w3.y, acc[j][1]);
            acc[j][2] = fmaf(hv.w, w3.z, acc[j][2]);
            acc[j][3] = fmaf(hv.w, w3.w, acc[j][3]);
        }
    }

#pragma unroll
    for (int j = 0; j < 4; ++j) {
        int node = node0 + 4 * ny + j;
        if (node < n) {
            __half2 p01 = __floats2half2_rn(acc[j][0], acc[j][1]);
            __half2 p23 = __floats2half2_rn(acc[j][2], acc[j][3]);
            uint2 r;
            r.x = *(unsigned int*)&p01;
            r.y = *(unsigned int*)&p23;
            ((uint2*)hw)[(size_t)node * 16 + tx] = r;
        }
    }
}

// ---------------- gather: wave per node, wave-uniform edges, fp16 rows ----------------
// Per edge ONE coalesced 128B fp16 row load from a uniform base; 4 independent
// loads in flight; fp32 accumulate.
template <bool BUCKET>
__global__ __launch_bounds__(256) void k_gather(const __half* __restrict__ hw, const int* __restrict__ csr,
                                                const int* __restrict__ roff, const int* __restrict__ deg,
                                                const float* __restrict__ dinv, const float* __restrict__ bias,
                                                float* __restrict__ agg, int n) {
    int tid = threadIdx.x;
    int lane = tid & 63;
    int v = blockIdx.x * 4 + (tid >> 6);
    if (v >= n) return;
    int dcnt = deg[v];
    float dv = dinv[v];
    int cnt;
    const int* base;
    if (BUCKET) {
        cnt = min(dcnt, CAP);
        base = csr + (size_t)v * CAP;
    } else {
        cnt = dcnt;
        base = csr + (roff[v] - dcnt);
    }
    float acc = bias[lane] + __half2float(hw[(size_t)v * HIDW + lane]) * dv * dv;
    for (int j0 = 0; j0 < cnt; j0 += 64) {
        int m = min(cnt - j0, 64);
        int idx = (lane < m) ? base[j0 + lane] : 0;
        float wl = (lane < m) ? dinv[idx] * dv : 0.f;
        int j = 0;
        for (; j + 4 <= m; j += 4) {
            int a0 = __shfl(idx, j + 0); float w0 = __shfl(wl, j + 0);
            int a1 = __shfl(idx, j + 1); float w1 = __shfl(wl, j + 1);
            int a2 = __shfl(idx, j + 2); float w2 = __shfl(wl, j + 2);
            int a3 = __shfl(idx, j + 3); float w3 = __shfl(wl, j + 3);
            float f0 = __half2float(hw[(size_t)a0 * HIDW + lane]);
            float f1 = __half2float(hw[(size_t)a1 * HIDW + lane]);
            float f2 = __half2float(hw[(size_t)a2 * HIDW + lane]);
            float f3 = __half2float(hw[(size_t)a3 * HIDW + lane]);
            acc = fmaf(f0, w0, acc);
            acc = fmaf(f1, w1, acc);
            acc = fmaf(f2, w2, acc);
            acc = fmaf(f3, w3, acc);
        }
        for (; j < m; ++j) {
            int a = __shfl(idx, j);
            float w = __shfl(wl, j);
            acc = fmaf(__half2float(hw[(size_t)a * HIDW + lane]), w, acc);
        }
    }
    agg[(size_t)v * HIDW + lane] = acc;
}

// ---------------- BatchNorm (training-mode batch stats) + ReLU ----------------
__global__ void k_stats_zero(float* __restrict__ st) {
    int i = threadIdx.x;
    if (i < 128) st[i] = 0.f;
}

__global__ __launch_bounds__(256) void k_stats_acc(const float* __restrict__ a, float* __restrict__ st, int n) {
    __shared__ float ss[256];
    __shared__ float sq[256];
    int tid = threadIdx.x;
    int c = tid & 63;
    int r = tid >> 6;
    float s = 0.f, q = 0.f;
    for (int nd = blockIdx.x * 4 + r; nd < n; nd += gridDim.x * 4) {
        float v = a[(size_t)nd * HIDW + c];
        s += v;
        q += v * v;
    }
    ss[tid] = s;
    sq[tid] = q;
    __syncthreads();
    if (tid < 64) {
        float S = ss[tid] + ss[tid + 64] + ss[tid + 128] + ss[tid + 192];
        float Q = sq[tid] + sq[tid + 64] + sq[tid + 128] + sq[tid + 192];
        atomicAdd(&st[c], S);
        atomicAdd(&st[64 + c], Q);
    }
}

__global__ void k_stats_fin(float* __restrict__ st, float invn) {
    int c = threadIdx.x;
    if (c < 64) {
        float mu = st[c] * invn;
        float var = st[64 + c] * invn - mu * mu;
        var = fmaxf(var, 0.f);
        st[c] = mu;
        st[64 + c] = rsqrtf(var + EPSV);
    }
}

__global__ __launch_bounds__(256) void k_bn_relu(float* __restrict__ a, const float* __restrict__ st,
                                                 const float* __restrict__ g, const float* __restrict__ bt,
                                                 int total) {
    int i = blockIdx.x * 256 + threadIdx.x;
    if (i < total) {
        int c = i & 63;
        float y = (a[i] - st[c]) * st[64 + c] * g[c] + bt[c];
        a[i] = fmaxf(y, 0.f);
    }
}

// ---------------- MLP head ----------------
__global__ __launch_bounds__(256) void k_head(const float* __restrict__ h, const float* __restrict__ lw1,
                                              const float* __restrict__ lb1, const float* __restrict__ lw2,
                                              const float* __restrict__ lb2, float* __restrict__ out, int n) {
    __shared__ float sW[64 * 32];
    __shared__ float sb1[32];
    __shared__ float sw2[32];
    int tid = threadIdx.x;
    for (int i = tid; i < 64 * 32; i += 256) sW[i] = lw1[i];
    if (tid < 32) {
        sb1[tid] = lb1[tid];
        sw2[tid] = lw2[tid];
    }
    __syncthreads();
    int nd = blockIdx.x * 256 + tid;
    if (nd >= n) return;
    float acc[32];
#pragma unroll
    for (int j = 0; j < 32; ++j) acc[j] = sb1[j];
    const float4* hr = (const float4*)(h + (size_t)nd * HIDW);
#pragma unroll 4
    for (int kc = 0; kc < 16; ++kc) {
        float4 h4 = hr[kc];
        const float* w0 = &sW[(kc * 4 + 0) * 32];
        const float* w1 = &sW[(kc * 4 + 1) * 32];
        const float* w2 = &sW[(kc * 4 + 2) * 32];
        const float* w3 = &sW[(kc * 4 + 3) * 32];
#pragma unroll
        for (int j = 0; j < 32; ++j) {
            float t = fmaf(h4.x, w0[j], fmaf(h4.y, w1[j], fmaf(h4.z, w2[j], h4.w * w3[j])));
            acc[j] += t;
        }
    }
    float o = lb2[0];
#pragma unroll
    for (int j = 0; j < 32; ++j) o = fmaf(fmaxf(acc[j], 0.f), sw2[j], o);
    out[nd] = o;
}

// ---------------- launch ----------------
extern "C" void kernel_launch(void* const* d_in, const int* in_sizes, int n_in,
                              void* d_out, int out_size, void* d_ws, size_t ws_size,
                              hipStream_t stream) {
    const float* x = (const float*)d_in[0];
    const int* ei = (const int*)d_in[1];
    const float* W[3] = {(const float*)d_in[2], (const float*)d_in[6], (const float*)d_in[10]};
    const float* B[3] = {(const float*)d_in[3], (const float*)d_in[7], (const float*)d_in[11]};
    const float* G[3] = {(const float*)d_in[4], (const float*)d_in[8], (const float*)d_in[12]};
    const float* BT[3] = {(const float*)d_in[5], (const float*)d_in[9], (const float*)d_in[13]};
    const float* lw1 = (const float*)d_in[14];
    const float* lb1 = (const float*)d_in[15];
    const float* lw2 = (const float*)d_in[16];
    const float* lb2 = (const float*)d_in[17];
    float* out = (float*)d_out;

    const int n = in_sizes[0] / 128;  // 100000
    const int e = in_sizes[1] / 2;    // 1600000
    const int* srcv = ei;
    const int* dstv = ei + e;
    const int nf = (e + 31) / 32;     // flag words

    char* ws = (char*)d_ws;
    size_t off = 0;
    auto alloc = [&](size_t bytes) -> char* {
        off = (off + 511) & ~(size_t)511;
        char* p = ws + off;
        off += bytes;
        return p;
    };
    // common
    float* stats = (float*)alloc(512);
    int* ovfcnt = (int*)alloc(512);
    float* dinv = (float*)alloc((size_t)n * 4);
    int* deg = (int*)alloc((size_t)n * 4);
    float* bufA = (float*)alloc((size_t)n * HIDW * 4);
    __half* bufB = (__half*)alloc((size_t)n * HIDW * 2);
    size_t commonOff = off;

    // path A sizing: flags + bucket csr
    size_t needA = ((commonOff + 511) & ~(size_t)511) + (size_t)nf * 4;
    needA = ((needA + 511) & ~(size_t)511) + (size_t)n * CAP * 4;
    bool useA = (needA <= ws_size);

    const int gN = (n + 255) / 256;   // 391
    const int gE = (e + 255) / 256;   // 6250
    const int gG = (n + 63) / 64;     // 1563
    const int gV = (n + 3) / 4;       // 25000

    unsigned int* flags = nullptr;
    int* csrB = nullptr;
    int* roff = nullptr;
    int* bsum = nullptr;
    int* csrC = nullptr;

    if (useA) {
        flags = (unsigned int*)alloc((size_t)nf * 4);
        csrB = (int*)alloc((size_t)n * CAP * 4);
        k_zero<<<gN, 256, 0, stream>>>(deg, flags, ovfcnt, n, nf);
        k_build<<<gE * NPART, 256, 0, stream>>>(srcv, dstv, deg, csrB, flags, ovfcnt, e);
        k_dinv<<<gN, 256, 0, stream>>>(deg, dinv, n);
    } else {
        roff = (int*)alloc((size_t)(n + 1) * 4);
        bsum = (int*)alloc(512 * 4);
        csrC = (int*)alloc((size_t)e * 4);
        k_zero<<<gN, 256, 0, stream>>>(deg, (unsigned int*)bsum, ovfcnt, n, 0);
        k_count<<<gE, 256, 0, stream>>>(dstv, deg, e);
        k_scan1<<<gN, 256, 0, stream>>>(deg, roff, bsum, n);
        k_scan2<<<1, 512, 0, stream>>>(bsum, gN);
        k_scan3<<<gN, 256, 0, stream>>>(roff, bsum, n);
        k_dinv<<<gN, 256, 0, stream>>>(deg, dinv, n);
        k_fill2<<<gE, 256, 0, stream>>>(srcv, dstv, roff, csrC, e);
    }

    for (int L = 0; L < 3; ++L) {
        if (L == 0)
            k_gemm<128><<<gG, 256, 0, stream>>>(x, W[0], bufB, n);
        else
            k_gemm<64><<<gG, 256, 0, stream>>>(bufA, W[L], bufB, n);
        if (useA) {
            k_gather<true><<<gV, 256, 0, stream>>>(bufB, csrB, nullptr, deg, dinv, B[L], bufA, n);
            k_ovf<<<256, 256, 0, stream>>>(bufB, srcv, dstv, flags, ovfcnt, dinv, bufA, e);
        } else {
            k_gather<false><<<gV, 256, 0, stream>>>(bufB, csrC, roff, deg, dinv, B[L], bufA, n);
        }
        k_stats_zero<<<1, 128, 0, stream>>>(stats);
        k_stats_acc<<<200, 256, 0, stream>>>(bufA, stats, n);
        k_stats_fin<<<1, 64, 0, stream>>>(stats, 1.0f / (float)n);
        k_bn_relu<<<(n * HIDW + 255) / 256, 256, 0, stream>>>(bufA, stats, G[L], BT[L], n * HIDW);
    }

    k_head<<<gN, 256, 0, stream>>>(bufA, lw1, lb1, lw2, lb2, out, n);
}

// Round 7
// 540.761 us; speedup vs baseline: 2.6232x; 1.0814x over previous
//
#include <hip/hip_runtime.h>
#include <hip/hip_fp16.h>

// ---------------- constants ----------------
#define HIDW 64
#define EPSV 1e-5f
#define CAP 32     // bucket capacity; Poisson(16) P(deg>32) ~ 1e-4 -> overflow path
#define NPART 8    // XCD partitions for build locality

// ---------------- init: zero deg / flags / ovfcnt / 3 stats slots ----------------
__global__ __launch_bounds__(256) void k_zero(int* __restrict__ deg, unsigned int* __restrict__ flags,
                                              int* __restrict__ ovfcnt, float* __restrict__ stats,
                                              int n, int nf) {
    int i = blockIdx.x * 256 + threadIdx.x;
    if (i < n) deg[i] = 0;
    if (flags && i < nf) flags[i] = 0u;
    if (i == 0) ovfcnt[0] = 0;
    if (i < 384) stats[i] = 0.f;   // 3 layers x (64 sum + 64 sumsq)
}

// ---------------- build: fused count+fill, XCD-partitioned by dst range ----------------
__global__ __launch_bounds__(256) void k_build(const int* __restrict__ srcv, const int* __restrict__ dstv,
                                               int* __restrict__ deg, int* __restrict__ csr,
                                               unsigned int* __restrict__ flags, int* __restrict__ ovfcnt, int e) {
    int part = blockIdx.x & (NPART - 1);
    int i = (blockIdx.x >> 3) * 256 + threadIdx.x;
    if (i >= e) return;
    int d = dstv[i];
    if (((d >> 10) & (NPART - 1)) != part) return;
    int slot = atomicAdd(&deg[d], 1);
    if (slot < CAP) {
        csr[(size_t)d * CAP + slot] = srcv[i];
    } else {
        atomicOr(&flags[i >> 5], 1u << (i & 31));
        atomicAdd(ovfcnt, 1);
    }
}

// overflow edges (expected ~a dozen): applied after gather, before stats
__global__ __launch_bounds__(256) void k_ovf(const __half* __restrict__ hw, const int* __restrict__ srcv,
                                             const int* __restrict__ dstv, const unsigned int* __restrict__ flags,
                                             const int* __restrict__ ovfcnt, const float* __restrict__ dinv,
                                             float* __restrict__ agg, int e) {
    if (ovfcnt[0] == 0) return;
    int nw = (e + 31) >> 5;
    for (int w = blockIdx.x * 256 + threadIdx.x; w < nw; w += gridDim.x * 256) {
        unsigned int f = flags[w];
        while (f) {
            int b = __ffs(f) - 1;
            f &= f - 1;
            int i = w * 32 + b;
            int s = srcv[i], d = dstv[i];
            float wt = dinv[s] * dinv[d];
            for (int c = 0; c < HIDW; ++c)
                atomicAdd(&agg[(size_t)d * HIDW + c], __half2float(hw[(size_t)s * HIDW + c]) * wt);
        }
    }
}

// ---------------- path B (fallback, classic 2-pass CSR) ----------------
__global__ __launch_bounds__(256) void k_count(const int* __restrict__ dstv, int* __restrict__ deg, int e) {
    int i = blockIdx.x * 256 + threadIdx.x;
    if (i < e) atomicAdd(&deg[dstv[i]], 1);
}

__global__ __launch_bounds__(256) void k_scan1(const int* __restrict__ deg, int* __restrict__ off,
                                               int* __restrict__ bsum, int n) {
    __shared__ int s[256];
    int tid = threadIdx.x;
    int i = blockIdx.x * 256 + tid;
    int v = (i < n) ? deg[i] : 0;
    s[tid] = v;
    __syncthreads();
    for (int o = 1; o < 256; o <<= 1) {
        int t = (tid >= o) ? s[tid - o] : 0;
        __syncthreads();
        s[tid] += t;
        __syncthreads();
    }
    if (i < n) off[i] = s[tid] - v;
    if (tid == 255) bsum[blockIdx.x] = s[255];
}

__global__ __launch_bounds__(512) void k_scan2(int* __restrict__ bsum, int nb) {
    __shared__ int s[512];
    int tid = threadIdx.x;
    int v = (tid < nb) ? bsum[tid] : 0;
    s[tid] = v;
    __syncthreads();
    for (int o = 1; o < 512; o <<= 1) {
        int t = (tid >= o) ? s[tid - o] : 0;
        __syncthreads();
        s[tid] += t;
        __syncthreads();
    }
    if (tid < nb) bsum[tid] = s[tid] - v;
}

__global__ __launch_bounds__(256) void k_scan3(int* __restrict__ off, const int* __restrict__ bsum, int n) {
    int i = blockIdx.x * 256 + threadIdx.x;
    if (i < n) off[i] += bsum[blockIdx.x];
}

__global__ __launch_bounds__(256) void k_fill2(const int* __restrict__ srcv, const int* __restrict__ dstv,
                                               int* __restrict__ roff, int* __restrict__ csr, int e) {
    int i = blockIdx.x * 256 + threadIdx.x;
    if (i < e) {
        int d = dstv[i];
        int p = atomicAdd(&roff[d], 1);
        csr[p] = srcv[i];
    }
}

// ---------------- GEMM: hw[N,64] = f(h)[N,K] @ W[K,64], fp16 output ----------------
// BN=true: f(h) = relu((h-mu)*rstd*g+bt) computed from RAW stat sums during LDS
// staging (folds the old bn_relu + stats_fin kernels away). BN=false (layer 0):
// f=identity, and dinv[i]=rsqrt(1+deg[i]) is fused here (runs between build and
// gather0; grid*256 >= n).
template <int K, bool BN>
__global__ __launch_bounds__(256) void k_gemm(const float* __restrict__ h, const float* __restrict__ W,
                                              __half* __restrict__ hw, int n,
                                              const float* __restrict__ st, const float* __restrict__ g,
                                              const float* __restrict__ bt, float invn,
                                              const int* __restrict__ deg, float* __restrict__ dinv) {
    constexpr int KP = K + 4;
    constexpr int KQ = K / 4;
    __shared__ float sH[64 * KP];
    __shared__ float sW[K * 64];
    __shared__ float sSc[HIDW];
    __shared__ float sSh[HIDW];
    int tid = threadIdx.x;
    int node0 = blockIdx.x * 64;

    if (BN) {
        if (tid < HIDW) {
            float mu = st[tid] * invn;
            float var = st[HIDW + tid] * invn - mu * mu;
            var = fmaxf(var, 0.f);
            float rstd = rsqrtf(var + EPSV);
            float sc = rstd * g[tid];
            sSc[tid] = sc;
            sSh[tid] = bt[tid] - mu * sc;
        }
        __syncthreads();
    } else {
        // fused dinv (layer 0 only)
        int i = blockIdx.x * 256 + tid;
        if (i < n) dinv[i] = rsqrtf(1.0f + (float)deg[i]);
    }

    for (int i = tid; i < K * 16; i += 256)
        ((float4*)sW)[i] = ((const float4*)W)[i];
    for (int i = tid; i < 64 * KQ; i += 256) {
        int row = i / KQ, kq = i % KQ;
        int nn = node0 + row;
        if (nn >= n) nn = n - 1;
        float4 v = ((const float4*)h)[(size_t)nn * KQ + kq];
        if (BN) {
            int c = 4 * kq;
            v.x = fmaxf(fmaf(v.x, sSc[c + 0], sSh[c + 0]), 0.f);
            v.y = fmaxf(fmaf(v.y, sSc[c + 1], sSh[c + 1]), 0.f);
            v.z = fmaxf(fmaf(v.z, sSc[c + 2], sSh[c + 2]), 0.f);
            v.w = fmaxf(fmaf(v.w, sSc[c + 3], sSh[c + 3]), 0.f);
        }
        ((float4*)(sH + row * KP))[kq] = v;
    }
    __syncthreads();

    int tx = tid & 15;
    int ny = tid >> 4;
    const float* hbase = sH + (4 * ny) * KP;

    float acc[4][4];
#pragma unroll
    for (int j = 0; j < 4; ++j)
#pragma unroll
        for (int c = 0; c < 4; ++c) acc[j][c] = 0.f;

#pragma unroll 2
    for (int kq = 0; kq < KQ; ++kq) {
        float4 w0 = ((const float4*)(sW + (4 * kq + 0) * 64))[tx];
        float4 w1 = ((const float4*)(sW + (4 * kq + 1) * 64))[tx];
        float4 w2 = ((const float4*)(sW + (4 * kq + 2) * 64))[tx];
        float4 w3 = ((const float4*)(sW + (4 * kq + 3) * 64))[tx];
#pragma unroll
        for (int j = 0; j < 4; ++j) {
            float4 hv = ((const float4*)(hbase + j * KP))[kq];
            acc[j][0] = fmaf(hv.x, w0.x, acc[j][0]);
            acc[j][1] = fmaf(hv.x, w0.y, acc[j][1]);
            acc[j][2] = fmaf(hv.x, w0.z, acc[j][2]);
            acc[j][3] = fmaf(hv.x, w0.w, acc[j][3]);
            acc[j][0] = fmaf(hv.y, w1.x, acc[j][0]);
            acc[j][1] = fmaf(hv.y, w1.y, acc[j][1]);
            acc[j][2] = fmaf(hv.y, w1.z, acc[j][2]);
            acc[j][3] = fmaf(hv.y, w1.w, acc[j][3]);
            acc[j][0] = fmaf(hv.z, w2.x, acc[j][0]);
            acc[j][1] = fmaf(hv.z, w2.y, acc[j][1]);
            acc[j][2] = fmaf(hv.z, w2.z, acc[j][2]);
            acc[j][3] = fmaf(hv.z, w2.w, acc[j][3]);
            acc[j][0] = fmaf(hv.w, w3.x, acc[j][0]);
            acc[j][1] = fmaf(hv.w, w3.y, acc[j][1]);
            acc[j][2] = fmaf(hv.w, w3.z, acc[j][2]);
            acc[j][3] = fmaf(hv.w, w3.w, acc[j][3]);
        }
    }

#pragma unroll
    for (int j = 0; j < 4; ++j) {
        int node = node0 + 4 * ny + j;
        if (node < n) {
            __half2 p01 = __floats2half2_rn(acc[j][0], acc[j][1]);
            __half2 p23 = __floats2half2_rn(acc[j][2], acc[j][3]);
            uint2 r;
            r.x = *(unsigned int*)&p01;
            r.y = *(unsigned int*)&p23;
            ((uint2*)hw)[(size_t)node * 16 + tx] = r;
        }
    }
}

// ---------------- gather: wave per node, wave-uniform edges, fp16 rows ----------------
template <bool BUCKET>
__global__ __launch_bounds__(256) void k_gather(const __half* __restrict__ hw, const int* __restrict__ csr,
                                                const int* __restrict__ roff, const int* __restrict__ deg,
                                                const float* __restrict__ dinv, const float* __restrict__ bias,
                                                float* __restrict__ agg, int n) {
    int tid = threadIdx.x;
    int lane = tid & 63;
    int v = blockIdx.x * 4 + (tid >> 6);
    if (v >= n) return;
    int dcnt = deg[v];
    float dv = dinv[v];
    int cnt;
    const int* base;
    if (BUCKET) {
        cnt = min(dcnt, CAP);
        base = csr + (size_t)v * CAP;
    } else {
        cnt = dcnt;
        base = csr + (roff[v] - dcnt);
    }
    float acc = bias[lane] + __half2float(hw[(size_t)v * HIDW + lane]) * dv * dv;
    for (int j0 = 0; j0 < cnt; j0 += 64) {
        int m = min(cnt - j0, 64);
        int idx = (lane < m) ? base[j0 + lane] : 0;
        float wl = (lane < m) ? dinv[idx] * dv : 0.f;
        int j = 0;
        for (; j + 4 <= m; j += 4) {
            int a0 = __shfl(idx, j + 0); float w0 = __shfl(wl, j + 0);
            int a1 = __shfl(idx, j + 1); float w1 = __shfl(wl, j + 1);
            int a2 = __shfl(idx, j + 2); float w2 = __shfl(wl, j + 2);
            int a3 = __shfl(idx, j + 3); float w3 = __shfl(wl, j + 3);
            float f0 = __half2float(hw[(size_t)a0 * HIDW + lane]);
            float f1 = __half2float(hw[(size_t)a1 * HIDW + lane]);
            float f2 = __half2float(hw[(size_t)a2 * HIDW + lane]);
            float f3 = __half2float(hw[(size_t)a3 * HIDW + lane]);
            acc = fmaf(f0, w0, acc);
            acc = fmaf(f1, w1, acc);
            acc = fmaf(f2, w2, acc);
            acc = fmaf(f3, w3, acc);
        }
        for (; j < m; ++j) {
            int a = __shfl(idx, j);
            float w = __shfl(wl, j);
            acc = fmaf(__half2float(hw[(size_t)a * HIDW + lane]), w, acc);
        }
    }
    agg[(size_t)v * HIDW + lane] = acc;
}

// ---------------- per-layer raw stats (sum, sumsq) into its own slot ----------------
__global__ __launch_bounds__(256) void k_stats_acc(const float* __restrict__ a, float* __restrict__ st, int n) {
    __shared__ float ss[256];
    __shared__ float sq[256];
    int tid = threadIdx.x;
    int c = tid & 63;
    int r = tid >> 6;
    float s = 0.f, q = 0.f;
    for (int nd = blockIdx.x * 4 + r; nd < n; nd += gridDim.x * 4) {
        float v = a[(size_t)nd * HIDW + c];
        s += v;
        q += v * v;
    }
    ss[tid] = s;
    sq[tid] = q;
    __syncthreads();
    if (tid < 64) {
        float S = ss[tid] + ss[tid + 64] + ss[tid + 128] + ss[tid + 192];
        float Q = sq[tid] + sq[tid + 64] + sq[tid + 128] + sq[tid + 192];
        atomicAdd(&st[c], S);
        atomicAdd(&st[64 + c], Q);
    }
}

// ---------------- MLP head with layer-2 BN+ReLU folded in ----------------
__global__ __launch_bounds__(256) void k_head(const float* __restrict__ h, const float* __restrict__ lw1,
                                              const float* __restrict__ lb1, const float* __restrict__ lw2,
                                              const float* __restrict__ lb2, float* __restrict__ out, int n,
                                              const float* __restrict__ st, const float* __restrict__ g,
                                              const float* __restrict__ bt, float invn) {
    __shared__ float sW[64 * 32];
    __shared__ float sb1[32];
    __shared__ float sw2[32];
    __shared__ float sSc[HIDW];
    __shared__ float sSh[HIDW];
    int tid = threadIdx.x;
    for (int i = tid; i < 64 * 32; i += 256) sW[i] = lw1[i];
    if (tid < 32) {
        sb1[tid] = lb1[tid];
        sw2[tid] = lw2[tid];
    }
    if (tid < HIDW) {
        float mu = st[tid] * invn;
        float var = st[HIDW + tid] * invn - mu * mu;
        var = fmaxf(var, 0.f);
        float rstd = rsqrtf(var + EPSV);
        float sc = rstd * g[tid];
        sSc[tid] = sc;
        sSh[tid] = bt[tid] - mu * sc;
    }
    __syncthreads();
    int nd = blockIdx.x * 256 + tid;
    if (nd >= n) return;
    float acc[32];
#pragma unroll
    for (int j = 0; j < 32; ++j) acc[j] = sb1[j];
    const float4* hr = (const float4*)(h + (size_t)nd * HIDW);
#pragma unroll 4
    for (int kc = 0; kc < 16; ++kc) {
        float4 h4 = hr[kc];
        int c = 4 * kc;
        h4.x = fmaxf(fmaf(h4.x, sSc[c + 0], sSh[c + 0]), 0.f);
        h4.y = fmaxf(fmaf(h4.y, sSc[c + 1], sSh[c + 1]), 0.f);
        h4.z = fmaxf(fmaf(h4.z, sSc[c + 2], sSh[c + 2]), 0.f);
        h4.w = fmaxf(fmaf(h4.w, sSc[c + 3], sSh[c + 3]), 0.f);
        const float* w0 = &sW[(c + 0) * 32];
        const float* w1 = &sW[(c + 1) * 32];
        const float* w2 = &sW[(c + 2) * 32];
        const float* w3 = &sW[(c + 3) * 32];
#pragma unroll
        for (int j = 0; j < 32; ++j) {
            float t = fmaf(h4.x, w0[j], fmaf(h4.y, w1[j], fmaf(h4.z, w2[j], h4.w * w3[j])));
            acc[j] += t;
        }
    }
    float o = lb2[0];
#pragma unroll
    for (int j = 0; j < 32; ++j) o = fmaf(fmaxf(acc[j], 0.f), sw2[j], o);
    out[nd] = o;
}

// ---------------- launch ----------------
extern "C" void kernel_launch(void* const* d_in, const int* in_sizes, int n_in,
                              void* d_out, int out_size, void* d_ws, size_t ws_size,
                              hipStream_t stream) {
    const float* x = (const float*)d_in[0];
    const int* ei = (const int*)d_in[1];
    const float* W[3] = {(const float*)d_in[2], (const float*)d_in[6], (const float*)d_in[10]};
    const float* B[3] = {(const float*)d_in[3], (const float*)d_in[7], (const float*)d_in[11]};
    const float* G[3] = {(const float*)d_in[4], (const float*)d_in[8], (const float*)d_in[12]};
    const float* BT[3] = {(const float*)d_in[5], (const float*)d_in[9], (const float*)d_in[13]};
    const float* lw1 = (const float*)d_in[14];
    const float* lb1 = (const float*)d_in[15];
    const float* lw2 = (const float*)d_in[16];
    const float* lb2 = (const float*)d_in[17];
    float* out = (float*)d_out;

    const int n = in_sizes[0] / 128;  // 100000
    const int e = in_sizes[1] / 2;    // 1600000
    const int* srcv = ei;
    const int* dstv = ei + e;
    const int nf = (e + 31) / 32;
    const float invn = 1.0f / (float)n;

    char* ws = (char*)d_ws;
    size_t off = 0;
    auto alloc = [&](size_t bytes) -> char* {
        off = (off + 511) & ~(size_t)511;
        char* p = ws + off;
        off += bytes;
        return p;
    };
    float* stats = (float*)alloc(3 * 128 * 4);   // 3 slots x (sum64 + sumsq64)
    int* ovfcnt = (int*)alloc(512);
    float* dinv = (float*)alloc((size_t)n * 4);
    int* deg = (int*)alloc((size_t)n * 4);
    float* bufA = (float*)alloc((size_t)n * HIDW * 4);
    __half* bufB = (__half*)alloc((size_t)n * HIDW * 2);
    size_t commonOff = off;

    size_t needA = ((commonOff + 511) & ~(size_t)511) + (size_t)nf * 4;
    needA = ((needA + 511) & ~(size_t)511) + (size_t)n * CAP * 4;
    bool useA = (needA <= ws_size);

    const int gN = (n + 255) / 256;   // 391
    const int gE = (e + 255) / 256;   // 6250
    const int gG = (n + 63) / 64;     // 1563
    const int gV = (n + 3) / 4;       // 25000

    unsigned int* flags = nullptr;
    int* csrB = nullptr;
    int* roff = nullptr;
    int* bsum = nullptr;
    int* csrC = nullptr;

    if (useA) {
        flags = (unsigned int*)alloc((size_t)nf * 4);
        csrB = (int*)alloc((size_t)n * CAP * 4);
        k_zero<<<gN, 256, 0, stream>>>(deg, flags, ovfcnt, stats, n, nf);
        k_build<<<gE * NPART, 256, 0, stream>>>(srcv, dstv, deg, csrB, flags, ovfcnt, e);
    } else {
        roff = (int*)alloc((size_t)(n + 1) * 4);
        bsum = (int*)alloc(512 * 4);
        csrC = (int*)alloc((size_t)e * 4);
        k_zero<<<gN, 256, 0, stream>>>(deg, nullptr, ovfcnt, stats, n, 0);
        k_count<<<gE, 256, 0, stream>>>(dstv, deg, e);
        k_scan1<<<gN, 256, 0, stream>>>(deg, roff, bsum, n);
        k_scan2<<<1, 512, 0, stream>>>(bsum, gN);
        k_scan3<<<gN, 256, 0, stream>>>(roff, bsum, n);
        k_fill2<<<gE, 256, 0, stream>>>(srcv, dstv, roff, csrC, e);
    }

    for (int L = 0; L < 3; ++L) {
        if (L == 0)
            k_gemm<128, false><<<gG, 256, 0, stream>>>(x, W[0], bufB, n, nullptr, nullptr, nullptr, invn,
                                                       deg, dinv);   // dinv fused here
        else
            k_gemm<64, true><<<gG, 256, 0, stream>>>(bufA, W[L], bufB, n, stats + (L - 1) * 128,
                                                     G[L - 1], BT[L - 1], invn, nullptr, nullptr);
        if (useA) {
            k_gather<true><<<gV, 256, 0, stream>>>(bufB, csrB, nullptr, deg, dinv, B[L], bufA, n);
            k_ovf<<<64, 256, 0, stream>>>(bufB, srcv, dstv, flags, ovfcnt, dinv, bufA, e);
        } else {
            k_gather<false><<<gV, 256, 0, stream>>>(bufB, csrC, roff, deg, dinv, B[L], bufA, n);
        }
        k_stats_acc<<<200, 256, 0, stream>>>(bufA, stats + L * 128, n);
    }

    k_head<<<gN, 256, 0, stream>>>(bufA, lw1, lb1, lw2, lb2, out, n, stats + 2 * 128, G[2], BT[2], invn);
}

// Round 8
// 456.935 us; speedup vs baseline: 3.1044x; 1.1835x over previous
//
#include <hip/hip_runtime.h>
#include <hip/hip_fp16.h>

// ---------------- constants ----------------
#define HIDW 64
#define EPSV 1e-5f
#define CAP 32     // bucket capacity; Poisson(16): ~10 nodes overflow -> ovf path
#define NPART 8    // XCD partitions for build locality
#define NSLOT 64   // partial BN-stat slots (contention vs merge-cost tradeoff)

// ---------------- init: zero deg / flags / ovfcnt / 3 x NSLOT stat slots ----------------
__global__ __launch_bounds__(256) void k_zero(int* __restrict__ deg, unsigned int* __restrict__ flags,
                                              int* __restrict__ ovfcnt, float* __restrict__ stats,
                                              int n, int nf) {
    int i = blockIdx.x * 256 + threadIdx.x;
    if (i < n) deg[i] = 0;
    if (flags && i < nf) flags[i] = 0u;
    if (i == 0) ovfcnt[0] = 0;
    if (i < 3 * NSLOT * 128) stats[i] = 0.f;
}

// ---------------- build: fused count+fill, XCD-partitioned by dst range ----------------
__global__ __launch_bounds__(256) void k_build(const int* __restrict__ srcv, const int* __restrict__ dstv,
                                               int* __restrict__ deg, int* __restrict__ csr,
                                               unsigned int* __restrict__ flags, int* __restrict__ ovfcnt, int e) {
    int part = blockIdx.x & (NPART - 1);
    int i = (blockIdx.x >> 3) * 256 + threadIdx.x;
    if (i >= e) return;
    int d = dstv[i];
    if (((d >> 10) & (NPART - 1)) != part) return;
    int slot = atomicAdd(&deg[d], 1);
    if (slot < CAP) {
        csr[(size_t)d * CAP + slot] = srcv[i];
    } else {
        atomicOr(&flags[i >> 5], 1u << (i & 31));
        atomicAdd(ovfcnt, 1);
    }
}

// overflow edges (~10 nodes): added to agg AFTER gather. hw rows are pre-scaled
// by dinv[src], so the weight is dinv[dst] only. These contributions are absent
// from the fused BN sums: shifts mu by ~5e-5 absolute (negligible vs 4.8e-2).
__global__ __launch_bounds__(256) void k_ovf(const __half* __restrict__ hw, const int* __restrict__ srcv,
                                             const int* __restrict__ dstv, const unsigned int* __restrict__ flags,
                                             const int* __restrict__ ovfcnt, const int* __restrict__ deg,
                                             float* __restrict__ agg, int e) {
    if (ovfcnt[0] == 0) return;
    int nw = (e + 31) >> 5;
    for (int w = blockIdx.x * 256 + threadIdx.x; w < nw; w += gridDim.x * 256) {
        unsigned int f = flags[w];
        while (f) {
            int b = __ffs(f) - 1;
            f &= f - 1;
            int i = w * 32 + b;
            int s = srcv[i], d = dstv[i];
            float wt = rsqrtf(1.0f + (float)deg[d]);
            for (int c = 0; c < HIDW; ++c)
                atomicAdd(&agg[(size_t)d * HIDW + c], __half2float(hw[(size_t)s * HIDW + c]) * wt);
        }
    }
}

// ---------------- path B (fallback, classic 2-pass CSR) ----------------
__global__ __launch_bounds__(256) void k_count(const int* __restrict__ dstv, int* __restrict__ deg, int e) {
    int i = blockIdx.x * 256 + threadIdx.x;
    if (i < e) atomicAdd(&deg[dstv[i]], 1);
}

__global__ __launch_bounds__(256) void k_scan1(const int* __restrict__ deg, int* __restrict__ off,
                                               int* __restrict__ bsum, int n) {
    __shared__ int s[256];
    int tid = threadIdx.x;
    int i = blockIdx.x * 256 + tid;
    int v = (i < n) ? deg[i] : 0;
    s[tid] = v;
    __syncthreads();
    for (int o = 1; o < 256; o <<= 1) {
        int t = (tid >= o) ? s[tid - o] : 0;
        __syncthreads();
        s[tid] += t;
        __syncthreads();
    }
    if (i < n) off[i] = s[tid] - v;
    if (tid == 255) bsum[blockIdx.x] = s[255];
}

__global__ __launch_bounds__(512) void k_scan2(int* __restrict__ bsum, int nb) {
    __shared__ int s[512];
    int tid = threadIdx.x;
    int v = (tid < nb) ? bsum[tid] : 0;
    s[tid] = v;
    __syncthreads();
    for (int o = 1; o < 512; o <<= 1) {
        int t = (tid >= o) ? s[tid - o] : 0;
        __syncthreads();
        s[tid] += t;
        __syncthreads();
    }
    if (tid < nb) bsum[tid] = s[tid] - v;
}

__global__ __launch_bounds__(256) void k_scan3(int* __restrict__ off, const int* __restrict__ bsum, int n) {
    int i = blockIdx.x * 256 + threadIdx.x;
    if (i < n) off[i] += bsum[blockIdx.x];
}

__global__ __launch_bounds__(256) void k_fill2(const int* __restrict__ srcv, const int* __restrict__ dstv,
                                               int* __restrict__ roff, int* __restrict__ csr, int e) {
    int i = blockIdx.x * 256 + threadIdx.x;
    if (i < e) {
        int d = dstv[i];
        int p = atomicAdd(&roff[d], 1);
        csr[p] = srcv[i];
    }
}

// ---------------- GEMM: hw[N,64] = dinv .* ( f(h)[N,K] @ W[K,64] ), fp16 output ----------------
// BN=true: f = relu(BN(h)) with scale/shift derived from the NSLOT partial raw
// sums merged in the prologue. Epilogue pre-scales each output row by
// dinv[node] = rsqrt(1+deg[node]) so the gather needs no per-edge weights.
template <int K, bool BN>
__global__ __launch_bounds__(256) void k_gemm(const float* __restrict__ h, const float* __restrict__ W,
                                              __half* __restrict__ hw, int n,
                                              const float* __restrict__ st, const float* __restrict__ g,
                                              const float* __restrict__ bt, float invn,
                                              const int* __restrict__ deg) {
    constexpr int KP = K + 4;
    constexpr int KQ = K / 4;
    __shared__ float sH[64 * KP];
    __shared__ float sW[K * 64];
    __shared__ float sM[128];
    __shared__ float sSc[HIDW];
    __shared__ float sSh[HIDW];
    int tid = threadIdx.x;
    int node0 = blockIdx.x * 64;

    if (BN) {
        if (tid < 128) {
            float t = 0.f;
#pragma unroll 8
            for (int s = 0; s < NSLOT; ++s) t += st[s * 128 + tid];
            sM[tid] = t;
        }
        __syncthreads();
        if (tid < HIDW) {
            float mu = sM[tid] * invn;
            float var = sM[HIDW + tid] * invn - mu * mu;
            var = fmaxf(var, 0.f);
            float rstd = rsqrtf(var + EPSV);
            float sc = rstd * g[tid];
            sSc[tid] = sc;
            sSh[tid] = bt[tid] - mu * sc;
        }
        __syncthreads();
    }

    for (int i = tid; i < K * 16; i += 256)
        ((float4*)sW)[i] = ((const float4*)W)[i];
    for (int i = tid; i < 64 * KQ; i += 256) {
        int row = i / KQ, kq = i % KQ;
        int nn = node0 + row;
        if (nn >= n) nn = n - 1;
        float4 v = ((const float4*)h)[(size_t)nn * KQ + kq];
        if (BN) {
            int c = 4 * kq;
            v.x = fmaxf(fmaf(v.x, sSc[c + 0], sSh[c + 0]), 0.f);
            v.y = fmaxf(fmaf(v.y, sSc[c + 1], sSh[c + 1]), 0.f);
            v.z = fmaxf(fmaf(v.z, sSc[c + 2], sSh[c + 2]), 0.f);
            v.w = fmaxf(fmaf(v.w, sSc[c + 3], sSh[c + 3]), 0.f);
        }
        ((float4*)(sH + row * KP))[kq] = v;
    }
    __syncthreads();

    int tx = tid & 15;
    int ny = tid >> 4;
    const float* hbase = sH + (4 * ny) * KP;

    float acc[4][4];
#pragma unroll
    for (int j = 0; j < 4; ++j)
#pragma unroll
        for (int c = 0; c < 4; ++c) acc[j][c] = 0.f;

#pragma unroll 2
    for (int kq = 0; kq < KQ; ++kq) {
        float4 w0 = ((const float4*)(sW + (4 * kq + 0) * 64))[tx];
        float4 w1 = ((const float4*)(sW + (4 * kq + 1) * 64))[tx];
        float4 w2 = ((const float4*)(sW + (4 * kq + 2) * 64))[tx];
        float4 w3 = ((const float4*)(sW + (4 * kq + 3) * 64))[tx];
#pragma unroll
        for (int j = 0; j < 4; ++j) {
            float4 hv = ((const float4*)(hbase + j * KP))[kq];
            acc[j][0] = fmaf(hv.x, w0.x, acc[j][0]);
            acc[j][1] = fmaf(hv.x, w0.y, acc[j][1]);
            acc[j][2] = fmaf(hv.x, w0.z, acc[j][2]);
            acc[j][3] = fmaf(hv.x, w0.w, acc[j][3]);
            acc[j][0] = fmaf(hv.y, w1.x, acc[j][0]);
            acc[j][1] = fmaf(hv.y, w1.y, acc[j][1]);
            acc[j][2] = fmaf(hv.y, w1.z, acc[j][2]);
            acc[j][3] = fmaf(hv.y, w1.w, acc[j][3]);
            acc[j][0] = fmaf(hv.z, w2.x, acc[j][0]);
            acc[j][1] = fmaf(hv.z, w2.y, acc[j][1]);
            acc[j][2] = fmaf(hv.z, w2.z, acc[j][2]);
            acc[j][3] = fmaf(hv.z, w2.w, acc[j][3]);
            acc[j][0] = fmaf(hv.w, w3.x, acc[j][0]);
            acc[j][1] = fmaf(hv.w, w3.y, acc[j][1]);
            acc[j][2] = fmaf(hv.w, w3.z, acc[j][2]);
            acc[j][3] = fmaf(hv.w, w3.w, acc[j][3]);
        }
    }

#pragma unroll
    for (int j = 0; j < 4; ++j) {
        int node = node0 + 4 * ny + j;
        if (node < n) {
            float dv = rsqrtf(1.0f + (float)deg[node]);
            __half2 p01 = __floats2half2_rn(acc[j][0] * dv, acc[j][1] * dv);
            __half2 p23 = __floats2half2_rn(acc[j][2] * dv, acc[j][3] * dv);
            uint2 r;
            r.x = *(unsigned int*)&p01;
            r.y = *(unsigned int*)&p23;
            ((uint2*)hw)[(size_t)node * 16 + tx] = r;
        }
    }
}

// ---------------- gather: wave per node, pre-scaled fp16 rows, fused BN stats ----------------
// agg[v] = bias + dinv[v] * (hw_st[v] + sum_a hw_st[a]); no per-edge weights.
// Block then LDS-reduces its 4 nodes' agg into (sum,sumsq) and atomicAdds one
// of NSLOT partial stat slots (merged in the next kernel's BN prologue).
template <bool BUCKET>
__global__ __launch_bounds__(256) void k_gather(const __half* __restrict__ hw, const int* __restrict__ csr,
                                                const int* __restrict__ roff, const int* __restrict__ deg,
                                                const float* __restrict__ bias,
                                                float* __restrict__ agg, float* __restrict__ st, int n) {
    __shared__ float ss[256];
    __shared__ float sq[256];
    int tid = threadIdx.x;
    int lane = tid & 63;
    int v = blockIdx.x * 4 + (tid >> 6);
    bool valid = (v < n);
    int vv = valid ? v : 0;
    int dcnt = deg[vv];
    float dv = rsqrtf(1.0f + (float)dcnt);
    int cnt;
    const int* base;
    if (BUCKET) {
        cnt = min(dcnt, CAP);
        base = csr + (size_t)vv * CAP;
    } else {
        cnt = dcnt;
        base = csr + (roff[vv] - dcnt);
    }
    float racc = __half2float(hw[(size_t)vv * HIDW + lane]);  // self row (pre-scaled)
    for (int j0 = 0; j0 < cnt; j0 += 64) {
        int m = min(cnt - j0, 64);
        int idx = (lane < m) ? base[j0 + lane] : 0;
        int j = 0;
        for (; j + 4 <= m; j += 4) {
            int a0 = __shfl(idx, j + 0);
            int a1 = __shfl(idx, j + 1);
            int a2 = __shfl(idx, j + 2);
            int a3 = __shfl(idx, j + 3);
            float f0 = __half2float(hw[(size_t)a0 * HIDW + lane]);
            float f1 = __half2float(hw[(size_t)a1 * HIDW + lane]);
            float f2 = __half2float(hw[(size_t)a2 * HIDW + lane]);
            float f3 = __half2float(hw[(size_t)a3 * HIDW + lane]);
            racc += (f0 + f1) + (f2 + f3);
        }
        for (; j < m; ++j) {
            int a = __shfl(idx, j);
            racc += __half2float(hw[(size_t)a * HIDW + lane]);
        }
    }
    float fin = fmaf(dv, racc, bias[lane]);
    if (valid) agg[(size_t)vv * HIDW + lane] = fin;
    float s = valid ? fin : 0.f;
    ss[tid] = s;
    sq[tid] = s * s;
    __syncthreads();
    if (tid < 64) {
        float S = ss[tid] + ss[tid + 64] + ss[tid + 128] + ss[tid + 192];
        float Q = sq[tid] + sq[tid + 64] + sq[tid + 128] + sq[tid + 192];
        float* slot = st + (size_t)(blockIdx.x & (NSLOT - 1)) * 128;
        atomicAdd(&slot[tid], S);
        atomicAdd(&slot[64 + tid], Q);
    }
}

// ---------------- MLP head with layer-2 BN+ReLU folded in ----------------
__global__ __launch_bounds__(256) void k_head(const float* __restrict__ h, const float* __restrict__ lw1,
                                              const float* __restrict__ lb1, const float* __restrict__ lw2,
                                              const float* __restrict__ lb2, float* __restrict__ out, int n,
                                              const float* __restrict__ st, const float* __restrict__ g,
                                              const float* __restrict__ bt, float invn) {
    __shared__ float sW[64 * 32];
    __shared__ float sb1[32];
    __shared__ float sw2[32];
    __shared__ float sM[128];
    __shared__ float sSc[HIDW];
    __shared__ float sSh[HIDW];
    int tid = threadIdx.x;
    for (int i = tid; i < 64 * 32; i += 256) sW[i] = lw1[i];
    if (tid < 32) {
        sb1[tid] = lb1[tid];
        sw2[tid] = lw2[tid];
    }
    if (tid < 128) {
        float t = 0.f;
#pragma unroll 8
        for (int s = 0; s < NSLOT; ++s) t += st[s * 128 + tid];
        sM[tid] = t;
    }
    __syncthreads();
    if (tid < HIDW) {
        float mu = sM[tid] * invn;
        float var = sM[HIDW + tid] * invn - mu * mu;
        var = fmaxf(var, 0.f);
        float rstd = rsqrtf(var + EPSV);
        float sc = rstd * g[tid];
        sSc[tid] = sc;
        sSh[tid] = bt[tid] - mu * sc;
    }
    __syncthreads();
    int nd = blockIdx.x * 256 + tid;
    if (nd >= n) return;
    float acc[32];
#pragma unroll
    for (int j = 0; j < 32; ++j) acc[j] = sb1[j];
    const float4* hr = (const float4*)(h + (size_t)nd * HIDW);
#pragma unroll 4
    for (int kc = 0; kc < 16; ++kc) {
        float4 h4 = hr[kc];
        int c = 4 * kc;
        h4.x = fmaxf(fmaf(h4.x, sSc[c + 0], sSh[c + 0]), 0.f);
        h4.y = fmaxf(fmaf(h4.y, sSc[c + 1], sSh[c + 1]), 0.f);
        h4.z = fmaxf(fmaf(h4.z, sSc[c + 2], sSh[c + 2]), 0.f);
        h4.w = fmaxf(fmaf(h4.w, sSc[c + 3], sSh[c + 3]), 0.f);
        const float* w0 = &sW[(c + 0) * 32];
        const float* w1 = &sW[(c + 1) * 32];
        const float* w2 = &sW[(c + 2) * 32];
        const float* w3 = &sW[(c + 3) * 32];
#pragma unroll
        for (int j = 0; j < 32; ++j) {
            float t = fmaf(h4.x, w0[j], fmaf(h4.y, w1[j], fmaf(h4.z, w2[j], h4.w * w3[j])));
            acc[j] += t;
        }
    }
    float o = lb2[0];
#pragma unroll
    for (int j = 0; j < 32; ++j) o = fmaf(fmaxf(acc[j], 0.f), sw2[j], o);
    out[nd] = o;
}

// ---------------- launch ----------------
extern "C" void kernel_launch(void* const* d_in, const int* in_sizes, int n_in,
                              void* d_out, int out_size, void* d_ws, size_t ws_size,
                              hipStream_t stream) {
    const float* x = (const float*)d_in[0];
    const int* ei = (const int*)d_in[1];
    const float* W[3] = {(const float*)d_in[2], (const float*)d_in[6], (const float*)d_in[10]};
    const float* B[3] = {(const float*)d_in[3], (const float*)d_in[7], (const float*)d_in[11]};
    const float* G[3] = {(const float*)d_in[4], (const float*)d_in[8], (const float*)d_in[12]};
    const float* BT[3] = {(const float*)d_in[5], (const float*)d_in[9], (const float*)d_in[13]};
    const float* lw1 = (const float*)d_in[14];
    const float* lb1 = (const float*)d_in[15];
    const float* lw2 = (const float*)d_in[16];
    const float* lb2 = (const float*)d_in[17];
    float* out = (float*)d_out;

    const int n = in_sizes[0] / 128;  // 100000
    const int e = in_sizes[1] / 2;    // 1600000
    const int* srcv = ei;
    const int* dstv = ei + e;
    const int nf = (e + 31) / 32;
    const float invn = 1.0f / (float)n;

    char* ws = (char*)d_ws;
    size_t off = 0;
    auto alloc = [&](size_t bytes) -> char* {
        off = (off + 511) & ~(size_t)511;
        char* p = ws + off;
        off += bytes;
        return p;
    };
    float* stats = (float*)alloc((size_t)3 * NSLOT * 128 * 4);  // 3 layers x NSLOT x (sum64+sumsq64)
    int* ovfcnt = (int*)alloc(512);
    int* deg = (int*)alloc((size_t)n * 4);
    float* bufA = (float*)alloc((size_t)n * HIDW * 4);
    __half* bufB = (__half*)alloc((size_t)n * HIDW * 2);
    size_t commonOff = off;

    size_t needA = ((commonOff + 511) & ~(size_t)511) + (size_t)nf * 4;
    needA = ((needA + 511) & ~(size_t)511) + (size_t)n * CAP * 4;
    bool useA = (needA <= ws_size);

    const int gN = (n + 255) / 256;   // 391
    const int gE = (e + 255) / 256;   // 6250
    const int gG = (n + 63) / 64;     // 1563
    const int gV = (n + 3) / 4;       // 25000

    unsigned int* flags = nullptr;
    int* csrB = nullptr;
    int* roff = nullptr;
    int* bsum = nullptr;
    int* csrC = nullptr;

    if (useA) {
        flags = (unsigned int*)alloc((size_t)nf * 4);
        csrB = (int*)alloc((size_t)n * CAP * 4);
        k_zero<<<gN, 256, 0, stream>>>(deg, flags, ovfcnt, stats, n, nf);
        k_build<<<gE * NPART, 256, 0, stream>>>(srcv, dstv, deg, csrB, flags, ovfcnt, e);
    } else {
        roff = (int*)alloc((size_t)(n + 1) * 4);
        bsum = (int*)alloc(512 * 4);
        csrC = (int*)alloc((size_t)e * 4);
        k_zero<<<gN, 256, 0, stream>>>(deg, nullptr, ovfcnt, stats, n, 0);
        k_count<<<gE, 256, 0, stream>>>(dstv, deg, e);
        k_scan1<<<gN, 256, 0, stream>>>(deg, roff, bsum, n);
        k_scan2<<<1, 512, 0, stream>>>(bsum, gN);
        k_scan3<<<gN, 256, 0, stream>>>(roff, bsum, n);
        k_fill2<<<gE, 256, 0, stream>>>(srcv, dstv, roff, csrC, e);
    }

    for (int L = 0; L < 3; ++L) {
        float* stL = stats + (size_t)L * NSLOT * 128;
        if (L == 0)
            k_gemm<128, false><<<gG, 256, 0, stream>>>(x, W[0], bufB, n, nullptr, nullptr, nullptr, invn, deg);
        else
            k_gemm<64, true><<<gG, 256, 0, stream>>>(bufA, W[L], bufB, n, stats + (size_t)(L - 1) * NSLOT * 128,
                                                     G[L - 1], BT[L - 1], invn, deg);
        if (useA) {
            k_gather<true><<<gV, 256, 0, stream>>>(bufB, csrB, nullptr, deg, B[L], bufA, stL, n);
            k_ovf<<<64, 256, 0, stream>>>(bufB, srcv, dstv, flags, ovfcnt, deg, bufA, e);
        } else {
            k_gather<false><<<gV, 256, 0, stream>>>(bufB, csrC, roff, deg, B[L], bufA, stL, n);
        }
    }

    k_head<<<gN, 256, 0, stream>>>(bufA, lw1, lb1, lw2, lb2, out, n, stats + (size_t)2 * NSLOT * 128,
                                   G[2], BT[2], invn);
}